// Round 1
// baseline (1418.277 us; speedup 1.0000x reference)
//
#include <hip/hip_runtime.h>

typedef __bf16 bf16_t;
typedef bf16_t bf16x8 __attribute__((ext_vector_type(8)));
typedef bf16_t bf16x4 __attribute__((ext_vector_type(4)));
typedef float  f32x4  __attribute__((ext_vector_type(4)));

#define NWIN 4096
#define CDIM 256
#define NTOK 64
#define NH   8

// LDS (58368 B total; 2 blocks/CU = 116736 <= 163840):
//  region0 [0, 40960) — time-shared:
//    phase 1-2 : xs [64][264] bf16 (x^T staged, row pad 264) = 33792 B
//    attention : per-wave scratch buf0 = region0 + w*5120 (5120 B each):
//                Q [64][40] -> K [64][40] -> V [32][72] -> P-halves [64][40]
//    phase 6-7 : o_lds [64][264] bf16 = 33792 B
//  mask [40960, 58368): mask [64][68] f32 (row pad 68 -> 2-way on column reads)
#define OFF_MASK  40960
#define LDS_BYTES 58368

__device__ __forceinline__ f32x4 mfma16(bf16x8 a, bf16x8 b, f32x4 c) {
    return __builtin_amdgcn_mfma_f32_16x16x32_bf16(a, b, c, 0, 0, 0);
}

template<bool USE_WS>
__launch_bounds__(512, 4)
__global__ void win_attn_kernel(const float* __restrict__ x,
                                const float* __restrict__ mask,
                                const float* __restrict__ qkv_w,
                                const float* __restrict__ qkv_b,
                                const float* __restrict__ proj_w,
                                const float* __restrict__ proj_b,
                                const float* __restrict__ bias_table,
                                const bf16_t* __restrict__ qkv_wb,
                                const bf16_t* __restrict__ proj_wb,
                                float* __restrict__ out)
{
    __shared__ __attribute__((aligned(16))) unsigned char smem[LDS_BYTES];
    bf16_t* xs       = (bf16_t*)smem;            // phase 1-2
    bf16_t* o_lds    = (bf16_t*)smem;            // phase 6-7
    float*  mask_lds = (float*)(smem + OFF_MASK);

    const int b    = blockIdx.x;
    const int tid  = threadIdx.x;
    const int w    = tid >> 6;        // wave id == head id
    const int lane = tid & 63;
    const int quad = lane >> 4;
    const int l15  = lane & 15;
    bf16_t* buf0 = (bf16_t*)(smem + w * 5120);   // per-wave scratch (attention)

    // ---- Phase 1: stage x[b] ([256][64] f32 -> xs[n][c] bf16) + mask (padded f32)
    {
        const float* xb = x + (size_t)b * (CDIM * NTOK);
        #pragma unroll
        for (int cb = 0; cb < 4; ++cb) {
            const int c0 = cb * 64 + w * 8;
            float v[8];
            #pragma unroll
            for (int j = 0; j < 8; ++j) v[j] = xb[(c0 + j) * 64 + lane];  // coalesced dwords
            bf16x8 t;
            #pragma unroll
            for (int j = 0; j < 8; ++j) t[j] = (bf16_t)v[j];
            *(bf16x8*)(xs + lane * 264 + c0) = t;                          // b128, 2-way
        }
        const float* mb = mask + (size_t)b * (NTOK * NTOK);
        #pragma unroll
        for (int it = 0; it < 2; ++it) {
            int e = (it * 512 + tid) * 4;
            int n = e >> 6, m = e & 63;
            f32x4 mv = *(const f32x4*)(mb + e);
            *(f32x4*)(mask_lds + n * 68 + m) = mv;
        }
    }
    __syncthreads();

    // ---- Phase 2: per-head QKV. Wave h computes its own head's 96 rows.
    //      q/k: normal order (d on quad/reg, n on lanes)  -> [n][d] LDS writes along d
    //      v  : swapped operands (n on quad/reg, d on lanes) -> [d][m] LDS writes along m
    const int h = w;
    f32x4 aqk[4][4];   // rt 0-1 = q tiles, rt 2-3 = k tiles
    f32x4 av[4][2];    // [ct][rtl] : V[d=rtl*16+l15][m=ct*16+quad*4+reg]
    #pragma unroll
    for (int rt = 0; rt < 4; ++rt)
        #pragma unroll
        for (int ct = 0; ct < 4; ++ct) aqk[rt][ct] = (f32x4){0.f,0.f,0.f,0.f};
    #pragma unroll
    for (int ct = 0; ct < 4; ++ct)
        #pragma unroll
        for (int rtl = 0; rtl < 2; ++rtl) av[ct][rtl] = (f32x4){0.f,0.f,0.f,0.f};

    for (int kk = 0; kk < 8; ++kk) {
        const int c0 = kk * 32;
        bf16x8 afr[6];
        #pragma unroll
        for (int rt = 0; rt < 6; ++rt) {
            int row = ((rt >> 1) << 8) + h * 32 + ((rt & 1) << 4) + l15;
            if constexpr (USE_WS) {
                afr[rt] = *(const bf16x8*)(qkv_wb + row * CDIM + c0 + quad * 8);
            } else {
                const float* ap = qkv_w + row * CDIM + c0 + quad * 8;
                f32x4 a0 = *(const f32x4*)ap;
                f32x4 a1 = *(const f32x4*)(ap + 4);
                bf16x8 t;
                #pragma unroll
                for (int j = 0; j < 4; ++j) { t[j] = (bf16_t)a0[j]; t[j+4] = (bf16_t)a1[j]; }
                afr[rt] = t;
            }
        }
        bf16x8 bfr[4];
        #pragma unroll
        for (int ct = 0; ct < 4; ++ct)
            bfr[ct] = *(const bf16x8*)(xs + (ct * 16 + l15) * 264 + c0 + quad * 8);
        #pragma unroll
        for (int rt = 0; rt < 4; ++rt)
            #pragma unroll
            for (int ct = 0; ct < 4; ++ct)
                aqk[rt][ct] = mfma16(afr[rt], bfr[ct], aqk[rt][ct]);
        #pragma unroll
        for (int ct = 0; ct < 4; ++ct)
            #pragma unroll
            for (int rtl = 0; rtl < 2; ++rtl)
                av[ct][rtl] = mfma16(bfr[ct], afr[4 + rtl], av[ct][rtl]);
    }
    __syncthreads();   // xs dead; region0 becomes per-wave scratch

    const float scale = 0.17677669529663687f;

    // ---- Q -> buf0 [64][40] (scale folded in), read qa fragments
    #pragma unroll
    for (int rtl = 0; rtl < 2; ++rtl) {
        f32x4 b4 = *(const f32x4*)(qkv_b + h * 32 + rtl * 16 + quad * 4);
        #pragma unroll
        for (int ct = 0; ct < 4; ++ct) {
            bf16x4 pk;
            #pragma unroll
            for (int r = 0; r < 4; ++r) pk[r] = (bf16_t)((aqk[rtl][ct][r] + b4[r]) * scale);
            *(bf16x4*)(buf0 + (ct * 16 + l15) * 40 + rtl * 16 + quad * 4) = pk;
        }
    }
    bf16x8 qa[4];
    #pragma unroll
    for (int nt = 0; nt < 4; ++nt)
        qa[nt] = *(const bf16x8*)(buf0 + (nt * 16 + l15) * 40 + quad * 8);

    // ---- K -> buf0 (overwrite), read kb fragments
    #pragma unroll
    for (int rtl = 0; rtl < 2; ++rtl) {
        f32x4 b4 = *(const f32x4*)(qkv_b + 256 + h * 32 + rtl * 16 + quad * 4);
        #pragma unroll
        for (int ct = 0; ct < 4; ++ct) {
            bf16x4 pk;
            #pragma unroll
            for (int r = 0; r < 4; ++r) pk[r] = (bf16_t)(aqk[2 + rtl][ct][r] + b4[r]);
            *(bf16x4*)(buf0 + (ct * 16 + l15) * 40 + rtl * 16 + quad * 4) = pk;
        }
    }
    bf16x8 kb[4];
    #pragma unroll
    for (int mt = 0; mt < 4; ++mt)
        kb[mt] = *(const bf16x8*)(buf0 + (mt * 16 + l15) * 40 + quad * 8);

    // ---- V -> buf0 as [32][72] (vectorized along m)
    #pragma unroll
    for (int rtl = 0; rtl < 2; ++rtl) {
        float bv = qkv_b[512 + h * 32 + rtl * 16 + l15];
        #pragma unroll
        for (int ct = 0; ct < 4; ++ct) {
            bf16x4 pk;
            #pragma unroll
            for (int r = 0; r < 4; ++r) pk[r] = (bf16_t)(av[ct][rtl][r] + bv);
            *(bf16x4*)(buf0 + (rtl * 16 + l15) * 72 + ct * 16 + quad * 4) = pk;
        }
    }

    // ---- S^T = mfma(kb, qa): m on (quad,reg), n on lanes
    f32x4 sacc[4][4];   // [mt][nt]
    #pragma unroll
    for (int mt = 0; mt < 4; ++mt)
        #pragma unroll
        for (int nt = 0; nt < 4; ++nt)
            sacc[mt][nt] = mfma16(kb[mt], qa[nt], (f32x4){0.f,0.f,0.f,0.f});

    // ---- softmax (rows n = nt*16 + l15; m = mt*16 + quad*4 + reg); 2 shuffles per reduce
    float inv[4];
    {
        const int qhi = quad >> 1, qlo = quad & 1;
        const int nwv = (l15 & 7) + 7 - 4 * qlo;   // (nw - mw0 + 7)
        const int nh_ = l15 >> 3;
        #pragma unroll
        for (int nt = 0; nt < 4; ++nt) {
            const int n = nt * 16 + l15;
            #pragma unroll
            for (int mt = 0; mt < 4; ++mt) {
                f32x4 mv = *(const f32x4*)(mask_lds + n * 68 + mt * 16 + quad * 4);
                int base = (nt * 2 + nh_ - 2 * mt - qhi + 7) * 15 + nwv;
                #pragma unroll
                for (int r = 0; r < 4; ++r)
                    sacc[mt][nt][r] += bias_table[(base - r) * NH + h] + mv[r];
            }
            float mx = sacc[0][nt][0];
            #pragma unroll
            for (int mt = 0; mt < 4; ++mt)
                #pragma unroll
                for (int r = 0; r < 4; ++r) mx = fmaxf(mx, sacc[mt][nt][r]);
            mx = fmaxf(mx, __shfl_xor(mx, 16, 64));
            mx = fmaxf(mx, __shfl_xor(mx, 32, 64));
            float s = 0.f;
            #pragma unroll
            for (int mt = 0; mt < 4; ++mt)
                #pragma unroll
                for (int r = 0; r < 4; ++r) {
                    float e = __expf(sacc[mt][nt][r] - mx);
                    sacc[mt][nt][r] = e;
                    s += e;
                }
            s += __shfl_xor(s, 16, 64);
            s += __shfl_xor(s, 32, 64);
            inv[nt] = __builtin_amdgcn_rcpf(s);
        }
    }

    // ---- PV: read vb, then P halves through buf0. O^T = mfma(vb, pb).
    bf16x8 vb[2][2];
    #pragma unroll
    for (int dt = 0; dt < 2; ++dt)
        #pragma unroll
        for (int ch = 0; ch < 2; ++ch)
            vb[dt][ch] = *(const bf16x8*)(buf0 + (dt * 16 + l15) * 72 + ch * 32 + quad * 8);

    f32x4 oaccT[2][4];   // [dt][nt]: d on (quad,reg), n on lanes
    #pragma unroll
    for (int dt = 0; dt < 2; ++dt)
        #pragma unroll
        for (int nt = 0; nt < 4; ++nt) oaccT[dt][nt] = (f32x4){0.f,0.f,0.f,0.f};

    #pragma unroll
    for (int ch = 0; ch < 2; ++ch) {
        #pragma unroll
        for (int mt2 = 0; mt2 < 2; ++mt2) {   // mt = 2*ch + mt2
            #pragma unroll
            for (int nt = 0; nt < 4; ++nt) {
                bf16x4 pk;
                #pragma unroll
                for (int r = 0; r < 4; ++r) pk[r] = (bf16_t)sacc[2 * ch + mt2][nt][r];
                *(bf16x4*)(buf0 + (nt * 16 + l15) * 40 + mt2 * 16 + quad * 4) = pk;
            }
        }
        #pragma unroll
        for (int nt = 0; nt < 4; ++nt) {
            bf16x8 pb = *(const bf16x8*)(buf0 + (nt * 16 + l15) * 40 + quad * 8);
            #pragma unroll
            for (int dt = 0; dt < 2; ++dt)
                oaccT[dt][nt] = mfma16(vb[dt][ch], pb, oaccT[dt][nt]);
        }
    }
    __syncthreads();   // all waves done with scratch; region0 becomes o_lds

    // ---- Phase 6: O -> o_lds[n][c] (normalize by inv here; vectorized bf16x4 along c)
    #pragma unroll
    for (int dt = 0; dt < 2; ++dt)
        #pragma unroll
        for (int nt = 0; nt < 4; ++nt) {
            bf16x4 pk;
            #pragma unroll
            for (int r = 0; r < 4; ++r) pk[r] = (bf16_t)(oaccT[dt][nt][r] * inv[nt]);
            *(bf16x4*)(o_lds + (nt * 16 + l15) * 264 + h * 32 + dt * 16 + quad * 4) = pk;
        }
    __syncthreads();

    // ---- Phase 7: Y^T[e][n] = proj_w(e,:) . O(n,:); wave w -> e in [w*32, w*32+32)
    {
        f32x4 yacc[2][4];
        #pragma unroll
        for (int rt = 0; rt < 2; ++rt)
            #pragma unroll
            for (int ct = 0; ct < 4; ++ct) yacc[rt][ct] = (f32x4){0.f,0.f,0.f,0.f};

        for (int kk = 0; kk < 8; ++kk) {
            const int c0 = kk * 32;
            bf16x8 afr[2];
            #pragma unroll
            for (int rt = 0; rt < 2; ++rt) {
                int e = w * 32 + rt * 16 + l15;
                if constexpr (USE_WS) {
                    afr[rt] = *(const bf16x8*)(proj_wb + e * CDIM + c0 + quad * 8);
                } else {
                    const float* ap = proj_w + e * CDIM + c0 + quad * 8;
                    f32x4 a0 = *(const f32x4*)ap;
                    f32x4 a1 = *(const f32x4*)(ap + 4);
                    bf16x8 t;
                    #pragma unroll
                    for (int j = 0; j < 4; ++j) { t[j] = (bf16_t)a0[j]; t[j+4] = (bf16_t)a1[j]; }
                    afr[rt] = t;
                }
            }
            bf16x8 bfr[4];
            #pragma unroll
            for (int ct = 0; ct < 4; ++ct)
                bfr[ct] = *(const bf16x8*)(o_lds + (ct * 16 + l15) * 264 + c0 + quad * 8);
            #pragma unroll
            for (int rt = 0; rt < 2; ++rt)
                #pragma unroll
                for (int ct = 0; ct < 4; ++ct)
                    yacc[rt][ct] = mfma16(afr[rt], bfr[ct], yacc[rt][ct]);
        }
        float* ob = out + (size_t)b * (NTOK * CDIM);
        #pragma unroll
        for (int rt = 0; rt < 2; ++rt) {
            int e0 = w * 32 + rt * 16 + quad * 4;
            f32x4 pb4 = *(const f32x4*)(proj_b + e0);
            #pragma unroll
            for (int ct = 0; ct < 4; ++ct) {
                int n = ct * 16 + l15;
                f32x4 r = yacc[rt][ct] + pb4;
                *(f32x4*)(ob + n * 256 + e0) = r;
            }
        }
    }
}

// Convert fp32 weights to bf16 once per launch (into workspace).
__global__ void cvt_weights(const float* __restrict__ qkv_w,
                            const float* __restrict__ proj_w,
                            bf16_t* __restrict__ qkv_wb,
                            bf16_t* __restrict__ proj_wb)
{
    int i = blockIdx.x * 256 + threadIdx.x;
    int base = i * 4;
    const float* src; bf16_t* dst;
    if (base < 196608) { src = qkv_w + base; dst = qkv_wb + base; }
    else { base -= 196608; src = proj_w + base; dst = proj_wb + base; }
    f32x4 v = *(const f32x4*)src;
    bf16x4 o;
    #pragma unroll
    for (int j = 0; j < 4; ++j) o[j] = (bf16_t)v[j];
    *(bf16x4*)dst = o;
}

extern "C" void kernel_launch(void* const* d_in, const int* in_sizes, int n_in,
                              void* d_out, int out_size, void* d_ws, size_t ws_size,
                              hipStream_t stream) {
    const float* x          = (const float*)d_in[0];
    const float* mask       = (const float*)d_in[1];
    const float* qkv_w      = (const float*)d_in[2];
    const float* qkv_b      = (const float*)d_in[3];
    const float* proj_w     = (const float*)d_in[4];
    const float* proj_b     = (const float*)d_in[5];
    const float* bias_table = (const float*)d_in[6];
    float* out = (float*)d_out;

    const size_t ws_needed = (size_t)(196608 + 65536) * sizeof(bf16_t);  // 524288 B
    if (ws_size >= ws_needed) {
        bf16_t* qkv_wb  = (bf16_t*)d_ws;
        bf16_t* proj_wb = qkv_wb + 196608;
        cvt_weights<<<256, 256, 0, stream>>>(qkv_w, proj_w, qkv_wb, proj_wb);
        win_attn_kernel<true><<<NWIN, 512, 0, stream>>>(
            x, mask, qkv_w, qkv_b, proj_w, proj_b, bias_table, qkv_wb, proj_wb, out);
    } else {
        win_attn_kernel<false><<<NWIN, 512, 0, stream>>>(
            x, mask, qkv_w, qkv_b, proj_w, proj_b, bias_table, nullptr, nullptr, out);
    }
}

// Round 2
// 1336.187 us; speedup vs baseline: 1.0614x; 1.0614x over previous
//
#include <hip/hip_runtime.h>

typedef __bf16 bf16_t;
typedef bf16_t bf16x8 __attribute__((ext_vector_type(8)));
typedef bf16_t bf16x4 __attribute__((ext_vector_type(4)));
typedef float  f32x4  __attribute__((ext_vector_type(4)));

#define NWIN 4096
#define CDIM 256
#define NTOK 64
#define NH   8

// LDS (58368 B total; 2 blocks/CU = 116736 <= 163840):
//  region0 [0, 40960) — time-shared:
//    phase 1-2 : xs [64][264] bf16 (x^T staged, row pad 264) = 33792 B
//    attention : per-wave scratch buf0 = region0 + w*5120 (5120 B each):
//                Q [64][40] -> K [64][40] -> V [32][72] -> P-halves [64][40]
//    phase 6-7 : o_lds [64][264] bf16 = 33792 B
//  mask [40960, 58368): mask [64][68] f32 (row pad 68 -> 2-way on column reads)
#define OFF_MASK  40960
#define LDS_BYTES 58368

__device__ __forceinline__ f32x4 mfma16(bf16x8 a, bf16x8 b, f32x4 c) {
    return __builtin_amdgcn_mfma_f32_16x16x32_bf16(a, b, c, 0, 0, 0);
}

template<bool USE_WS>
__launch_bounds__(512, 4)
__global__ void win_attn_kernel(const float* __restrict__ x,
                                const float* __restrict__ mask,
                                const float* __restrict__ qkv_w,
                                const float* __restrict__ qkv_b,
                                const float* __restrict__ proj_w,
                                const float* __restrict__ proj_b,
                                const float* __restrict__ bias_table,
                                const bf16_t* __restrict__ qkv_wb,
                                const bf16_t* __restrict__ proj_wb,
                                float* __restrict__ out)
{
    __shared__ __attribute__((aligned(16))) unsigned char smem[LDS_BYTES];
    bf16_t* xs       = (bf16_t*)smem;            // phase 1-2
    bf16_t* o_lds    = (bf16_t*)smem;            // phase 6-7
    float*  mask_lds = (float*)(smem + OFF_MASK);

    const int b    = blockIdx.x;
    const int tid  = threadIdx.x;
    const int w    = tid >> 6;        // wave id == head id
    const int lane = tid & 63;
    const int quad = lane >> 4;
    const int l15  = lane & 15;
    bf16_t* buf0 = (bf16_t*)(smem + w * 5120);   // per-wave scratch (attention)

    // ---- Phase 1: stage x[b] ([256][64] f32 -> xs[n][c] bf16) + mask (padded f32)
    {
        const float* xb = x + (size_t)b * (CDIM * NTOK);
        #pragma unroll
        for (int cb = 0; cb < 4; ++cb) {
            const int c0 = cb * 64 + w * 8;
            float v[8];
            #pragma unroll
            for (int j = 0; j < 8; ++j) v[j] = xb[(c0 + j) * 64 + lane];  // coalesced dwords
            bf16x8 t;
            #pragma unroll
            for (int j = 0; j < 8; ++j) t[j] = (bf16_t)v[j];
            *(bf16x8*)(xs + lane * 264 + c0) = t;                          // b128, 2-way
        }
        const float* mb = mask + (size_t)b * (NTOK * NTOK);
        #pragma unroll
        for (int it = 0; it < 2; ++it) {
            int e = (it * 512 + tid) * 4;
            int n = e >> 6, m = e & 63;
            f32x4 mv = *(const f32x4*)(mb + e);
            *(f32x4*)(mask_lds + n * 68 + m) = mv;
        }
    }
    __syncthreads();

    const int h = w;

    // ---- Phase 2a: V pass (swapped operands: d on lanes, m on quad/reg).
    //      Only 8 f32x4 accumulators live; result packed+biased into 16 regs (vpk).
    bf16x4 vpk[4][2];
    {
        f32x4 av[4][2];
        #pragma unroll
        for (int ct = 0; ct < 4; ++ct)
            #pragma unroll
            for (int rtl = 0; rtl < 2; ++rtl) av[ct][rtl] = (f32x4){0.f,0.f,0.f,0.f};

        for (int kk = 0; kk < 8; ++kk) {
            const int c0 = kk * 32;
            bf16x8 afr[2];
            #pragma unroll
            for (int rtl = 0; rtl < 2; ++rtl) {
                int row = 512 + h * 32 + rtl * 16 + l15;
                if constexpr (USE_WS) {
                    afr[rtl] = *(const bf16x8*)(qkv_wb + row * CDIM + c0 + quad * 8);
                } else {
                    const float* ap = qkv_w + row * CDIM + c0 + quad * 8;
                    f32x4 a0 = *(const f32x4*)ap;
                    f32x4 a1 = *(const f32x4*)(ap + 4);
                    bf16x8 t;
                    #pragma unroll
                    for (int j = 0; j < 4; ++j) { t[j] = (bf16_t)a0[j]; t[j+4] = (bf16_t)a1[j]; }
                    afr[rtl] = t;
                }
            }
            bf16x8 bfr[4];
            #pragma unroll
            for (int ct = 0; ct < 4; ++ct)
                bfr[ct] = *(const bf16x8*)(xs + (ct * 16 + l15) * 264 + c0 + quad * 8);
            #pragma unroll
            for (int ct = 0; ct < 4; ++ct)
                #pragma unroll
                for (int rtl = 0; rtl < 2; ++rtl)
                    av[ct][rtl] = mfma16(bfr[ct], afr[rtl], av[ct][rtl]);
        }
        #pragma unroll
        for (int rtl = 0; rtl < 2; ++rtl) {
            float bv = qkv_b[512 + h * 32 + rtl * 16 + l15];
            #pragma unroll
            for (int ct = 0; ct < 4; ++ct) {
                #pragma unroll
                for (int r = 0; r < 4; ++r) vpk[ct][rtl][r] = (bf16_t)(av[ct][rtl][r] + bv);
            }
        }
    }

    // ---- Phase 2b: Q+K pass (d on quad/reg, n on lanes). 16 f32x4 accumulators.
    f32x4 aqk[4][4];   // rt 0-1 = q tiles, rt 2-3 = k tiles
    #pragma unroll
    for (int rt = 0; rt < 4; ++rt)
        #pragma unroll
        for (int ct = 0; ct < 4; ++ct) aqk[rt][ct] = (f32x4){0.f,0.f,0.f,0.f};

    for (int kk = 0; kk < 8; ++kk) {
        const int c0 = kk * 32;
        bf16x8 afr[4];
        #pragma unroll
        for (int rt = 0; rt < 4; ++rt) {
            int row = ((rt >> 1) << 8) + h * 32 + ((rt & 1) << 4) + l15;
            if constexpr (USE_WS) {
                afr[rt] = *(const bf16x8*)(qkv_wb + row * CDIM + c0 + quad * 8);
            } else {
                const float* ap = qkv_w + row * CDIM + c0 + quad * 8;
                f32x4 a0 = *(const f32x4*)ap;
                f32x4 a1 = *(const f32x4*)(ap + 4);
                bf16x8 t;
                #pragma unroll
                for (int j = 0; j < 4; ++j) { t[j] = (bf16_t)a0[j]; t[j+4] = (bf16_t)a1[j]; }
                afr[rt] = t;
            }
        }
        bf16x8 bfr[4];
        #pragma unroll
        for (int ct = 0; ct < 4; ++ct)
            bfr[ct] = *(const bf16x8*)(xs + (ct * 16 + l15) * 264 + c0 + quad * 8);
        #pragma unroll
        for (int rt = 0; rt < 4; ++rt)
            #pragma unroll
            for (int ct = 0; ct < 4; ++ct)
                aqk[rt][ct] = mfma16(afr[rt], bfr[ct], aqk[rt][ct]);
    }
    __syncthreads();   // xs dead; region0 becomes per-wave scratch

    const float scale = 0.17677669529663687f;

    // ---- Q -> buf0 [64][40] (scale folded in), read qa fragments
    #pragma unroll
    for (int rtl = 0; rtl < 2; ++rtl) {
        f32x4 b4 = *(const f32x4*)(qkv_b + h * 32 + rtl * 16 + quad * 4);
        #pragma unroll
        for (int ct = 0; ct < 4; ++ct) {
            bf16x4 pk;
            #pragma unroll
            for (int r = 0; r < 4; ++r) pk[r] = (bf16_t)((aqk[rtl][ct][r] + b4[r]) * scale);
            *(bf16x4*)(buf0 + (ct * 16 + l15) * 40 + rtl * 16 + quad * 4) = pk;
        }
    }
    bf16x8 qa[4];
    #pragma unroll
    for (int nt = 0; nt < 4; ++nt)
        qa[nt] = *(const bf16x8*)(buf0 + (nt * 16 + l15) * 40 + quad * 8);

    // ---- K -> buf0 (overwrite), read kb fragments
    #pragma unroll
    for (int rtl = 0; rtl < 2; ++rtl) {
        f32x4 b4 = *(const f32x4*)(qkv_b + 256 + h * 32 + rtl * 16 + quad * 4);
        #pragma unroll
        for (int ct = 0; ct < 4; ++ct) {
            bf16x4 pk;
            #pragma unroll
            for (int r = 0; r < 4; ++r) pk[r] = (bf16_t)(aqk[2 + rtl][ct][r] + b4[r]);
            *(bf16x4*)(buf0 + (ct * 16 + l15) * 40 + rtl * 16 + quad * 4) = pk;
        }
    }
    bf16x8 kb[4];
    #pragma unroll
    for (int mt = 0; mt < 4; ++mt)
        kb[mt] = *(const bf16x8*)(buf0 + (mt * 16 + l15) * 40 + quad * 8);

    // ---- V -> buf0 as [32][72] from packed regs (vectorized along m)
    #pragma unroll
    for (int rtl = 0; rtl < 2; ++rtl)
        #pragma unroll
        for (int ct = 0; ct < 4; ++ct)
            *(bf16x4*)(buf0 + (rtl * 16 + l15) * 72 + ct * 16 + quad * 4) = vpk[ct][rtl];

    // ---- S^T = mfma(kb, qa): m on (quad,reg), n on lanes
    f32x4 sacc[4][4];   // [mt][nt]
    #pragma unroll
    for (int mt = 0; mt < 4; ++mt)
        #pragma unroll
        for (int nt = 0; nt < 4; ++nt)
            sacc[mt][nt] = mfma16(kb[mt], qa[nt], (f32x4){0.f,0.f,0.f,0.f});

    // ---- softmax (rows n = nt*16 + l15; m = mt*16 + quad*4 + reg); 2 shuffles per reduce
    //      P packed to bf16 immediately (ppk) so sacc dies before PV.
    float inv[4];
    bf16x4 ppk[4][4];   // [mt][nt]
    {
        const int qhi = quad >> 1, qlo = quad & 1;
        const int nwv = (l15 & 7) + 7 - 4 * qlo;   // (nw - mw0 + 7)
        const int nh_ = l15 >> 3;
        #pragma unroll
        for (int nt = 0; nt < 4; ++nt) {
            const int n = nt * 16 + l15;
            #pragma unroll
            for (int mt = 0; mt < 4; ++mt) {
                f32x4 mv = *(const f32x4*)(mask_lds + n * 68 + mt * 16 + quad * 4);
                int base = (nt * 2 + nh_ - 2 * mt - qhi + 7) * 15 + nwv;
                #pragma unroll
                for (int r = 0; r < 4; ++r)
                    sacc[mt][nt][r] += bias_table[(base - r) * NH + h] + mv[r];
            }
            float mx = sacc[0][nt][0];
            #pragma unroll
            for (int mt = 0; mt < 4; ++mt)
                #pragma unroll
                for (int r = 0; r < 4; ++r) mx = fmaxf(mx, sacc[mt][nt][r]);
            mx = fmaxf(mx, __shfl_xor(mx, 16, 64));
            mx = fmaxf(mx, __shfl_xor(mx, 32, 64));
            float s = 0.f;
            #pragma unroll
            for (int mt = 0; mt < 4; ++mt)
                #pragma unroll
                for (int r = 0; r < 4; ++r) {
                    float e = __expf(sacc[mt][nt][r] - mx);
                    ppk[mt][nt][r] = (bf16_t)e;
                    s += e;
                }
            s += __shfl_xor(s, 16, 64);
            s += __shfl_xor(s, 32, 64);
            inv[nt] = __builtin_amdgcn_rcpf(s);
        }
    }

    // ---- PV: read vb (before P overwrites V region!), then P halves through buf0.
    bf16x8 vb[2][2];
    #pragma unroll
    for (int dt = 0; dt < 2; ++dt)
        #pragma unroll
        for (int ch = 0; ch < 2; ++ch)
            vb[dt][ch] = *(const bf16x8*)(buf0 + (dt * 16 + l15) * 72 + ch * 32 + quad * 8);

    f32x4 oaccT[2][4];   // [dt][nt]: d on (quad,reg), n on lanes
    #pragma unroll
    for (int dt = 0; dt < 2; ++dt)
        #pragma unroll
        for (int nt = 0; nt < 4; ++nt) oaccT[dt][nt] = (f32x4){0.f,0.f,0.f,0.f};

    #pragma unroll
    for (int ch = 0; ch < 2; ++ch) {
        #pragma unroll
        for (int mt2 = 0; mt2 < 2; ++mt2) {   // mt = 2*ch + mt2
            #pragma unroll
            for (int nt = 0; nt < 4; ++nt)
                *(bf16x4*)(buf0 + (nt * 16 + l15) * 40 + mt2 * 16 + quad * 4) = ppk[2 * ch + mt2][nt];
        }
        #pragma unroll
        for (int nt = 0; nt < 4; ++nt) {
            bf16x8 pb = *(const bf16x8*)(buf0 + (nt * 16 + l15) * 40 + quad * 8);
            #pragma unroll
            for (int dt = 0; dt < 2; ++dt)
                oaccT[dt][nt] = mfma16(vb[dt][ch], pb, oaccT[dt][nt]);
        }
    }
    __syncthreads();   // all waves done with scratch; region0 becomes o_lds

    // ---- Phase 6: O -> o_lds[n][c] (normalize by inv here; vectorized bf16x4 along c)
    #pragma unroll
    for (int dt = 0; dt < 2; ++dt)
        #pragma unroll
        for (int nt = 0; nt < 4; ++nt) {
            bf16x4 pk;
            #pragma unroll
            for (int r = 0; r < 4; ++r) pk[r] = (bf16_t)(oaccT[dt][nt][r] * inv[nt]);
            *(bf16x4*)(o_lds + (nt * 16 + l15) * 264 + h * 32 + dt * 16 + quad * 4) = pk;
        }
    __syncthreads();

    // ---- Phase 7: Y^T[e][n] = proj_w(e,:) . O(n,:); wave w -> e in [w*32, w*32+32)
    {
        f32x4 yacc[2][4];
        #pragma unroll
        for (int rt = 0; rt < 2; ++rt)
            #pragma unroll
            for (int ct = 0; ct < 4; ++ct) yacc[rt][ct] = (f32x4){0.f,0.f,0.f,0.f};

        for (int kk = 0; kk < 8; ++kk) {
            const int c0 = kk * 32;
            bf16x8 afr[2];
            #pragma unroll
            for (int rt = 0; rt < 2; ++rt) {
                int e = w * 32 + rt * 16 + l15;
                if constexpr (USE_WS) {
                    afr[rt] = *(const bf16x8*)(proj_wb + e * CDIM + c0 + quad * 8);
                } else {
                    const float* ap = proj_w + e * CDIM + c0 + quad * 8;
                    f32x4 a0 = *(const f32x4*)ap;
                    f32x4 a1 = *(const f32x4*)(ap + 4);
                    bf16x8 t;
                    #pragma unroll
                    for (int j = 0; j < 4; ++j) { t[j] = (bf16_t)a0[j]; t[j+4] = (bf16_t)a1[j]; }
                    afr[rt] = t;
                }
            }
            bf16x8 bfr[4];
            #pragma unroll
            for (int ct = 0; ct < 4; ++ct)
                bfr[ct] = *(const bf16x8*)(o_lds + (ct * 16 + l15) * 264 + c0 + quad * 8);
            #pragma unroll
            for (int rt = 0; rt < 2; ++rt)
                #pragma unroll
                for (int ct = 0; ct < 4; ++ct)
                    yacc[rt][ct] = mfma16(afr[rt], bfr[ct], yacc[rt][ct]);
        }
        float* ob = out + (size_t)b * (NTOK * CDIM);
        #pragma unroll
        for (int rt = 0; rt < 2; ++rt) {
            int e0 = w * 32 + rt * 16 + quad * 4;
            f32x4 pb4 = *(const f32x4*)(proj_b + e0);
            #pragma unroll
            for (int ct = 0; ct < 4; ++ct) {
                int n = ct * 16 + l15;
                f32x4 r = yacc[rt][ct] + pb4;
                *(f32x4*)(ob + n * 256 + e0) = r;
            }
        }
    }
}

// Convert fp32 weights to bf16 once per launch (into workspace).
__global__ void cvt_weights(const float* __restrict__ qkv_w,
                            const float* __restrict__ proj_w,
                            bf16_t* __restrict__ qkv_wb,
                            bf16_t* __restrict__ proj_wb)
{
    int i = blockIdx.x * 256 + threadIdx.x;
    int base = i * 4;
    const float* src; bf16_t* dst;
    if (base < 196608) { src = qkv_w + base; dst = qkv_wb + base; }
    else { base -= 196608; src = proj_w + base; dst = proj_wb + base; }
    f32x4 v = *(const f32x4*)src;
    bf16x4 o;
    #pragma unroll
    for (int j = 0; j < 4; ++j) o[j] = (bf16_t)v[j];
    *(bf16x4*)dst = o;
}

extern "C" void kernel_launch(void* const* d_in, const int* in_sizes, int n_in,
                              void* d_out, int out_size, void* d_ws, size_t ws_size,
                              hipStream_t stream) {
    const float* x          = (const float*)d_in[0];
    const float* mask       = (const float*)d_in[1];
    const float* qkv_w      = (const float*)d_in[2];
    const float* qkv_b      = (const float*)d_in[3];
    const float* proj_w     = (const float*)d_in[4];
    const float* proj_b     = (const float*)d_in[5];
    const float* bias_table = (const float*)d_in[6];
    float* out = (float*)d_out;

    const size_t ws_needed = (size_t)(196608 + 65536) * sizeof(bf16_t);  // 524288 B
    if (ws_size >= ws_needed) {
        bf16_t* qkv_wb  = (bf16_t*)d_ws;
        bf16_t* proj_wb = qkv_wb + 196608;
        cvt_weights<<<256, 256, 0, stream>>>(qkv_w, proj_w, qkv_wb, proj_wb);
        win_attn_kernel<true><<<NWIN, 512, 0, stream>>>(
            x, mask, qkv_w, qkv_b, proj_w, proj_b, bias_table, qkv_wb, proj_wb, out);
    } else {
        win_attn_kernel<false><<<NWIN, 512, 0, stream>>>(
            x, mask, qkv_w, qkv_b, proj_w, proj_b, bias_table, nullptr, nullptr, out);
    }
}

// Round 3
// 1069.375 us; speedup vs baseline: 1.3263x; 1.2495x over previous
//
#include <hip/hip_runtime.h>

typedef __bf16 bf16_t;
typedef bf16_t bf16x8 __attribute__((ext_vector_type(8)));
typedef bf16_t bf16x4 __attribute__((ext_vector_type(4)));
typedef float  f32x4  __attribute__((ext_vector_type(4)));

#define NWIN 4096
#define CDIM 256
#define NTOK 64
#define NH   8

// LDS (58368 B total; 2 blocks/CU):
//  region0 [0, 40960) — time-shared:
//    phase 1-2 : xs [64][264] bf16 (x^T staged, row pad 264) = 33792 B
//    attention : per-wave scratch buf0 = region0 + w*5120 (5120 B each):
//                Q [64][40] -> K [64][40] -> V [32][72] -> P-halves [64][40]
//    phase 6-7 : o_lds [64][264] bf16 = 33792 B
//  mask [40960, 58368): mask [64][68] f32 (row pad 68 -> 2-way on column reads)
#define OFF_MASK  40960
#define LDS_BYTES 58368

__device__ __forceinline__ f32x4 mfma16(bf16x8 a, bf16x8 b, f32x4 c) {
    return __builtin_amdgcn_mfma_f32_16x16x32_bf16(a, b, c, 0, 0, 0);
}

template<bool USE_WS>
__launch_bounds__(512, 3)
__global__ void win_attn_kernel(const float* __restrict__ x,
                                const float* __restrict__ mask,
                                const float* __restrict__ qkv_w,
                                const float* __restrict__ qkv_b,
                                const float* __restrict__ proj_w,
                                const float* __restrict__ proj_b,
                                const float* __restrict__ bias_table,
                                const bf16_t* __restrict__ qkv_wb,
                                const bf16_t* __restrict__ proj_wb,
                                float* __restrict__ out)
{
    __shared__ __attribute__((aligned(16))) unsigned char smem[LDS_BYTES];
    bf16_t* xs       = (bf16_t*)smem;            // phase 1-2
    bf16_t* o_lds    = (bf16_t*)smem;            // phase 6-7
    float*  mask_lds = (float*)(smem + OFF_MASK);

    const int b    = blockIdx.x;
    const int tid  = threadIdx.x;
    const int w    = tid >> 6;        // wave id == head id
    const int lane = tid & 63;
    const int quad = lane >> 4;
    const int l15  = lane & 15;
    bf16_t* buf0 = (bf16_t*)(smem + w * 5120);   // per-wave scratch (attention)

    // ---- Phase 1: stage x[b] ([256][64] f32 -> xs[n][c] bf16) + mask (padded f32)
    {
        const float* xb = x + (size_t)b * (CDIM * NTOK);
        #pragma unroll
        for (int cb = 0; cb < 4; ++cb) {
            const int c0 = cb * 64 + w * 8;
            float v[8];
            #pragma unroll
            for (int j = 0; j < 8; ++j) v[j] = xb[(c0 + j) * 64 + lane];  // coalesced dwords
            bf16x8 t;
            #pragma unroll
            for (int j = 0; j < 8; ++j) t[j] = (bf16_t)v[j];
            *(bf16x8*)(xs + lane * 264 + c0) = t;                          // b128, 2-way
        }
        const float* mb = mask + (size_t)b * (NTOK * NTOK);
        #pragma unroll
        for (int it = 0; it < 2; ++it) {
            int e = (it * 512 + tid) * 4;
            int n = e >> 6, m = e & 63;
            f32x4 mv = *(const f32x4*)(mb + e);
            *(f32x4*)(mask_lds + n * 68 + m) = mv;
        }
    }
    __syncthreads();

    const int h = w;
    const float scale = 0.17677669529663687f;

    // ---- Phase 2: per-head QKV in THREE passes (cap live accumulators at 32 regs).
    //      Each pass: 8 f32x4 acc, result packed+biased to bf16 regs immediately.
    bf16x4 qpk[2][4];  // q[d=rtl*16+quad*4+r][n=ct*16+l15] (scale folded)
    bf16x4 kpk[2][4];  // k[d][n], same layout
    bf16x4 vpk[4][2];  // v[m=ct*16+quad*4+r][d=rtl*16+l15] (swapped orientation)

    #pragma unroll
    for (int sec = 0; sec < 2; ++sec) {   // 0 = Q, 1 = K
        f32x4 acc[2][4];
        #pragma unroll
        for (int rtl = 0; rtl < 2; ++rtl)
            #pragma unroll
            for (int ct = 0; ct < 4; ++ct) acc[rtl][ct] = (f32x4){0.f,0.f,0.f,0.f};

        for (int kk = 0; kk < 8; ++kk) {
            const int c0 = kk * 32;
            bf16x8 afr[2];
            #pragma unroll
            for (int rtl = 0; rtl < 2; ++rtl) {
                int row = sec * 256 + h * 32 + rtl * 16 + l15;
                if constexpr (USE_WS) {
                    afr[rtl] = *(const bf16x8*)(qkv_wb + row * CDIM + c0 + quad * 8);
                } else {
                    const float* ap = qkv_w + row * CDIM + c0 + quad * 8;
                    f32x4 a0 = *(const f32x4*)ap;
                    f32x4 a1 = *(const f32x4*)(ap + 4);
                    bf16x8 t;
                    #pragma unroll
                    for (int j = 0; j < 4; ++j) { t[j] = (bf16_t)a0[j]; t[j+4] = (bf16_t)a1[j]; }
                    afr[rtl] = t;
                }
            }
            bf16x8 bfr[4];
            #pragma unroll
            for (int ct = 0; ct < 4; ++ct)
                bfr[ct] = *(const bf16x8*)(xs + (ct * 16 + l15) * 264 + c0 + quad * 8);
            #pragma unroll
            for (int rtl = 0; rtl < 2; ++rtl)
                #pragma unroll
                for (int ct = 0; ct < 4; ++ct)
                    acc[rtl][ct] = mfma16(afr[rtl], bfr[ct], acc[rtl][ct]);
        }
        #pragma unroll
        for (int rtl = 0; rtl < 2; ++rtl) {
            f32x4 b4 = *(const f32x4*)(qkv_b + sec * 256 + h * 32 + rtl * 16 + quad * 4);
            #pragma unroll
            for (int ct = 0; ct < 4; ++ct) {
                #pragma unroll
                for (int r = 0; r < 4; ++r) {
                    float vv = acc[rtl][ct][r] + b4[r];
                    if (sec == 0) qpk[rtl][ct][r] = (bf16_t)(vv * scale);
                    else          kpk[rtl][ct][r] = (bf16_t)vv;
                }
            }
        }
    }
    {   // V pass (swapped operands: m on quad/reg, d on lanes)
        f32x4 acc[4][2];
        #pragma unroll
        for (int ct = 0; ct < 4; ++ct)
            #pragma unroll
            for (int rtl = 0; rtl < 2; ++rtl) acc[ct][rtl] = (f32x4){0.f,0.f,0.f,0.f};

        for (int kk = 0; kk < 8; ++kk) {
            const int c0 = kk * 32;
            bf16x8 afr[2];
            #pragma unroll
            for (int rtl = 0; rtl < 2; ++rtl) {
                int row = 512 + h * 32 + rtl * 16 + l15;
                if constexpr (USE_WS) {
                    afr[rtl] = *(const bf16x8*)(qkv_wb + row * CDIM + c0 + quad * 8);
                } else {
                    const float* ap = qkv_w + row * CDIM + c0 + quad * 8;
                    f32x4 a0 = *(const f32x4*)ap;
                    f32x4 a1 = *(const f32x4*)(ap + 4);
                    bf16x8 t;
                    #pragma unroll
                    for (int j = 0; j < 4; ++j) { t[j] = (bf16_t)a0[j]; t[j+4] = (bf16_t)a1[j]; }
                    afr[rtl] = t;
                }
            }
            bf16x8 bfr[4];
            #pragma unroll
            for (int ct = 0; ct < 4; ++ct)
                bfr[ct] = *(const bf16x8*)(xs + (ct * 16 + l15) * 264 + c0 + quad * 8);
            #pragma unroll
            for (int ct = 0; ct < 4; ++ct)
                #pragma unroll
                for (int rtl = 0; rtl < 2; ++rtl)
                    acc[ct][rtl] = mfma16(bfr[ct], afr[rtl], acc[ct][rtl]);
        }
        #pragma unroll
        for (int rtl = 0; rtl < 2; ++rtl) {
            float bv = qkv_b[512 + h * 32 + rtl * 16 + l15];
            #pragma unroll
            for (int ct = 0; ct < 4; ++ct)
                #pragma unroll
                for (int r = 0; r < 4; ++r) vpk[ct][rtl][r] = (bf16_t)(acc[ct][rtl][r] + bv);
        }
    }
    __syncthreads();   // xs dead; region0 becomes per-wave scratch

    // ---- Q -> buf0 [64][40] from packed regs, read qa fragments
    #pragma unroll
    for (int rtl = 0; rtl < 2; ++rtl)
        #pragma unroll
        for (int ct = 0; ct < 4; ++ct)
            *(bf16x4*)(buf0 + (ct * 16 + l15) * 40 + rtl * 16 + quad * 4) = qpk[rtl][ct];
    bf16x8 qa[4];
    #pragma unroll
    for (int nt = 0; nt < 4; ++nt)
        qa[nt] = *(const bf16x8*)(buf0 + (nt * 16 + l15) * 40 + quad * 8);

    // ---- K -> buf0 (overwrite), read kb fragments
    #pragma unroll
    for (int rtl = 0; rtl < 2; ++rtl)
        #pragma unroll
        for (int ct = 0; ct < 4; ++ct)
            *(bf16x4*)(buf0 + (ct * 16 + l15) * 40 + rtl * 16 + quad * 4) = kpk[rtl][ct];
    bf16x8 kb[4];
    #pragma unroll
    for (int mt = 0; mt < 4; ++mt)
        kb[mt] = *(const bf16x8*)(buf0 + (mt * 16 + l15) * 40 + quad * 8);

    // ---- V -> buf0 as [32][72] from packed regs (vectorized along m)
    #pragma unroll
    for (int rtl = 0; rtl < 2; ++rtl)
        #pragma unroll
        for (int ct = 0; ct < 4; ++ct)
            *(bf16x4*)(buf0 + (rtl * 16 + l15) * 72 + ct * 16 + quad * 4) = vpk[ct][rtl];

    // ---- S^T = mfma(kb, qa): m on (quad,reg), n on lanes
    f32x4 sacc[4][4];   // [mt][nt]
    #pragma unroll
    for (int mt = 0; mt < 4; ++mt)
        #pragma unroll
        for (int nt = 0; nt < 4; ++nt)
            sacc[mt][nt] = mfma16(kb[mt], qa[nt], (f32x4){0.f,0.f,0.f,0.f});

    // ---- softmax (rows n = nt*16 + l15; m = mt*16 + quad*4 + reg); 2 shuffles per reduce
    //      P packed to bf16 immediately (ppk) so sacc dies before PV.
    float inv[4];
    bf16x4 ppk[4][4];   // [mt][nt]
    {
        const int qhi = quad >> 1, qlo = quad & 1;
        const int nwv = (l15 & 7) + 7 - 4 * qlo;   // (nw - mw0 + 7)
        const int nh_ = l15 >> 3;
        #pragma unroll
        for (int nt = 0; nt < 4; ++nt) {
            const int n = nt * 16 + l15;
            #pragma unroll
            for (int mt = 0; mt < 4; ++mt) {
                f32x4 mv = *(const f32x4*)(mask_lds + n * 68 + mt * 16 + quad * 4);
                int base = (nt * 2 + nh_ - 2 * mt - qhi + 7) * 15 + nwv;
                #pragma unroll
                for (int r = 0; r < 4; ++r)
                    sacc[mt][nt][r] += bias_table[(base - r) * NH + h] + mv[r];
            }
            float mx = sacc[0][nt][0];
            #pragma unroll
            for (int mt = 0; mt < 4; ++mt)
                #pragma unroll
                for (int r = 0; r < 4; ++r) mx = fmaxf(mx, sacc[mt][nt][r]);
            mx = fmaxf(mx, __shfl_xor(mx, 16, 64));
            mx = fmaxf(mx, __shfl_xor(mx, 32, 64));
            float s = 0.f;
            #pragma unroll
            for (int mt = 0; mt < 4; ++mt)
                #pragma unroll
                for (int r = 0; r < 4; ++r) {
                    float e = __expf(sacc[mt][nt][r] - mx);
                    ppk[mt][nt][r] = (bf16_t)e;
                    s += e;
                }
            s += __shfl_xor(s, 16, 64);
            s += __shfl_xor(s, 32, 64);
            inv[nt] = __builtin_amdgcn_rcpf(s);
        }
    }

    // ---- PV: read vb (before P overwrites V region!), then P halves through buf0.
    bf16x8 vb[2][2];
    #pragma unroll
    for (int dt = 0; dt < 2; ++dt)
        #pragma unroll
        for (int ch = 0; ch < 2; ++ch)
            vb[dt][ch] = *(const bf16x8*)(buf0 + (dt * 16 + l15) * 72 + ch * 32 + quad * 8);

    f32x4 oaccT[2][4];   // [dt][nt]: d on (quad,reg), n on lanes
    #pragma unroll
    for (int dt = 0; dt < 2; ++dt)
        #pragma unroll
        for (int nt = 0; nt < 4; ++nt) oaccT[dt][nt] = (f32x4){0.f,0.f,0.f,0.f};

    #pragma unroll
    for (int ch = 0; ch < 2; ++ch) {
        #pragma unroll
        for (int mt2 = 0; mt2 < 2; ++mt2) {   // mt = 2*ch + mt2
            #pragma unroll
            for (int nt = 0; nt < 4; ++nt)
                *(bf16x4*)(buf0 + (nt * 16 + l15) * 40 + mt2 * 16 + quad * 4) = ppk[2 * ch + mt2][nt];
        }
        #pragma unroll
        for (int nt = 0; nt < 4; ++nt) {
            bf16x8 pb = *(const bf16x8*)(buf0 + (nt * 16 + l15) * 40 + quad * 8);
            #pragma unroll
            for (int dt = 0; dt < 2; ++dt)
                oaccT[dt][nt] = mfma16(vb[dt][ch], pb, oaccT[dt][nt]);
        }
    }
    __syncthreads();   // all waves done with scratch; region0 becomes o_lds

    // ---- Phase 6: O -> o_lds[n][c] (normalize by inv here; vectorized bf16x4 along c)
    #pragma unroll
    for (int dt = 0; dt < 2; ++dt)
        #pragma unroll
        for (int nt = 0; nt < 4; ++nt) {
            bf16x4 pk;
            #pragma unroll
            for (int r = 0; r < 4; ++r) pk[r] = (bf16_t)(oaccT[dt][nt][r] * inv[nt]);
            *(bf16x4*)(o_lds + (nt * 16 + l15) * 264 + h * 32 + dt * 16 + quad * 4) = pk;
        }
    __syncthreads();

    // ---- Phase 7: Y^T[e][n] = proj_w(e,:) . O(n,:); wave w -> e in [w*32, w*32+32)
    {
        f32x4 yacc[2][4];
        #pragma unroll
        for (int rt = 0; rt < 2; ++rt)
            #pragma unroll
            for (int ct = 0; ct < 4; ++ct) yacc[rt][ct] = (f32x4){0.f,0.f,0.f,0.f};

        for (int kk = 0; kk < 8; ++kk) {
            const int c0 = kk * 32;
            bf16x8 afr[2];
            #pragma unroll
            for (int rt = 0; rt < 2; ++rt) {
                int e = w * 32 + rt * 16 + l15;
                if constexpr (USE_WS) {
                    afr[rt] = *(const bf16x8*)(proj_wb + e * CDIM + c0 + quad * 8);
                } else {
                    const float* ap = proj_w + e * CDIM + c0 + quad * 8;
                    f32x4 a0 = *(const f32x4*)ap;
                    f32x4 a1 = *(const f32x4*)(ap + 4);
                    bf16x8 t;
                    #pragma unroll
                    for (int j = 0; j < 4; ++j) { t[j] = (bf16_t)a0[j]; t[j+4] = (bf16_t)a1[j]; }
                    afr[rt] = t;
                }
            }
            bf16x8 bfr[4];
            #pragma unroll
            for (int ct = 0; ct < 4; ++ct)
                bfr[ct] = *(const bf16x8*)(o_lds + (ct * 16 + l15) * 264 + c0 + quad * 8);
            #pragma unroll
            for (int rt = 0; rt < 2; ++rt)
                #pragma unroll
                for (int ct = 0; ct < 4; ++ct)
                    yacc[rt][ct] = mfma16(afr[rt], bfr[ct], yacc[rt][ct]);
        }
        float* ob = out + (size_t)b * (NTOK * CDIM);
        #pragma unroll
        for (int rt = 0; rt < 2; ++rt) {
            int e0 = w * 32 + rt * 16 + quad * 4;
            f32x4 pb4 = *(const f32x4*)(proj_b + e0);
            #pragma unroll
            for (int ct = 0; ct < 4; ++ct) {
                int n = ct * 16 + l15;
                f32x4 r = yacc[rt][ct] + pb4;
                *(f32x4*)(ob + n * 256 + e0) = r;
            }
        }
    }
}

// Convert fp32 weights to bf16 once per launch (into workspace).
__global__ void cvt_weights(const float* __restrict__ qkv_w,
                            const float* __restrict__ proj_w,
                            bf16_t* __restrict__ qkv_wb,
                            bf16_t* __restrict__ proj_wb)
{
    int i = blockIdx.x * 256 + threadIdx.x;
    int base = i * 4;
    const float* src; bf16_t* dst;
    if (base < 196608) { src = qkv_w + base; dst = qkv_wb + base; }
    else { base -= 196608; src = proj_w + base; dst = proj_wb + base; }
    f32x4 v = *(const f32x4*)src;
    bf16x4 o;
    #pragma unroll
    for (int j = 0; j < 4; ++j) o[j] = (bf16_t)v[j];
    *(bf16x4*)dst = o;
}

extern "C" void kernel_launch(void* const* d_in, const int* in_sizes, int n_in,
                              void* d_out, int out_size, void* d_ws, size_t ws_size,
                              hipStream_t stream) {
    const float* x          = (const float*)d_in[0];
    const float* mask       = (const float*)d_in[1];
    const float* qkv_w      = (const float*)d_in[2];
    const float* qkv_b      = (const float*)d_in[3];
    const float* proj_w     = (const float*)d_in[4];
    const float* proj_b     = (const float*)d_in[5];
    const float* bias_table = (const float*)d_in[6];
    float* out = (float*)d_out;

    const size_t ws_needed = (size_t)(196608 + 65536) * sizeof(bf16_t);  // 524288 B
    if (ws_size >= ws_needed) {
        bf16_t* qkv_wb  = (bf16_t*)d_ws;
        bf16_t* proj_wb = qkv_wb + 196608;
        cvt_weights<<<256, 256, 0, stream>>>(qkv_w, proj_w, qkv_wb, proj_wb);
        win_attn_kernel<true><<<NWIN, 512, 0, stream>>>(
            x, mask, qkv_w, qkv_b, proj_w, proj_b, bias_table, qkv_wb, proj_wb, out);
    } else {
        win_attn_kernel<false><<<NWIN, 512, 0, stream>>>(
            x, mask, qkv_w, qkv_b, proj_w, proj_b, bias_table, nullptr, nullptr, out);
    }
}

// Round 4
// 798.447 us; speedup vs baseline: 1.7763x; 1.3393x over previous
//
#include <hip/hip_runtime.h>

typedef __bf16 bf16_t;
typedef bf16_t bf16x8 __attribute__((ext_vector_type(8)));
typedef bf16_t bf16x4 __attribute__((ext_vector_type(4)));
typedef float  f32x4  __attribute__((ext_vector_type(4)));

#define NWIN 4096
#define CDIM 256
#define NTOK 64
#define NH   8

// LDS (58368 B total; 2 blocks/CU):
//  region0 [0, 40960) — time-shared:
//    phase 1-2 : xs [64][264] bf16 (x^T staged, row pad 264) = 33792 B
//    attention : per-wave scratch buf0 = region0 + w*5120 (5120 B each):
//                Q [64][40] -> K [64][40] -> V [32][72] -> P-halves [64][40]
//    phase 6-7 : o_lds [64][264] bf16 = 33792 B
//  mask [40960, 58368): mask [64][68] f32 (row pad 68 -> 2-way on column reads)
#define OFF_MASK  40960
#define LDS_BYTES 58368

__device__ __forceinline__ f32x4 mfma16(bf16x8 a, bf16x8 b, f32x4 c) {
    return __builtin_amdgcn_mfma_f32_16x16x32_bf16(a, b, c, 0, 0, 0);
}

template<bool USE_WS>
__launch_bounds__(512, 4)
__global__ void win_attn_kernel(const float* __restrict__ x,
                                const float* __restrict__ mask,
                                const float* __restrict__ qkv_w,
                                const float* __restrict__ qkv_b,
                                const float* __restrict__ proj_w,
                                const float* __restrict__ proj_b,
                                const float* __restrict__ bias_table,
                                const bf16_t* __restrict__ qkv_wb,
                                const bf16_t* __restrict__ proj_wb,
                                float* __restrict__ out)
{
    __shared__ __attribute__((aligned(16))) unsigned char smem[LDS_BYTES];
    bf16_t* xs       = (bf16_t*)smem;            // phase 1-2
    bf16_t* o_lds    = (bf16_t*)smem;            // phase 6-7
    float*  mask_lds = (float*)(smem + OFF_MASK);

    const int b    = blockIdx.x;
    const int tid  = threadIdx.x;
    const int w    = tid >> 6;        // wave id == head id
    const int lane = tid & 63;
    const int quad = lane >> 4;
    const int l15  = lane & 15;
    bf16_t* buf0 = (bf16_t*)(smem + w * 5120);   // per-wave scratch (attention)

    // ---- Phase 1: stage x[b] ([256][64] f32 -> xs[n][c] bf16) + mask (padded f32)
    {
        const float* xb = x + (size_t)b * (CDIM * NTOK);
        #pragma unroll
        for (int cb = 0; cb < 4; ++cb) {
            const int c0 = cb * 64 + w * 8;
            float v[8];
            #pragma unroll
            for (int j = 0; j < 8; ++j) v[j] = xb[(c0 + j) * 64 + lane];  // coalesced dwords
            bf16x8 t;
            #pragma unroll
            for (int j = 0; j < 8; ++j) t[j] = (bf16_t)v[j];
            *(bf16x8*)(xs + lane * 264 + c0) = t;                          // b128, 2-way
        }
        const float* mb = mask + (size_t)b * (NTOK * NTOK);
        #pragma unroll
        for (int it = 0; it < 2; ++it) {
            int e = (it * 512 + tid) * 4;
            int n = e >> 6, m = e & 63;
            f32x4 mv = *(const f32x4*)(mb + e);
            *(f32x4*)(mask_lds + n * 68 + m) = mv;
        }
    }
    __syncthreads();

    const int h = w;
    const float scale = 0.17677669529663687f;

    // ---- Phase 2: per-head QKV in THREE passes (cap live accumulators at 32 regs).
    //      Each pass: 8 f32x4 acc, result packed+biased to bf16 regs immediately.
    //      kk loops NOT unrolled (unroll 1) so the scheduler cannot hoist 8
    //      iterations of weight/xs loads into registers (that caused spills).
    bf16x4 qpk[2][4];  // q[d=rtl*16+quad*4+r][n=ct*16+l15] (scale folded)
    bf16x4 kpk[2][4];  // k[d][n], same layout
    bf16x4 vpk[4][2];  // v[m=ct*16+quad*4+r][d=rtl*16+l15] (swapped orientation)

    #pragma unroll
    for (int sec = 0; sec < 2; ++sec) {   // 0 = Q, 1 = K
        f32x4 acc[2][4];
        #pragma unroll
        for (int rtl = 0; rtl < 2; ++rtl)
            #pragma unroll
            for (int ct = 0; ct < 4; ++ct) acc[rtl][ct] = (f32x4){0.f,0.f,0.f,0.f};

        #pragma unroll 1
        for (int kk = 0; kk < 8; ++kk) {
            const int c0 = kk * 32;
            bf16x8 afr[2];
            #pragma unroll
            for (int rtl = 0; rtl < 2; ++rtl) {
                int row = sec * 256 + h * 32 + rtl * 16 + l15;
                if constexpr (USE_WS) {
                    afr[rtl] = *(const bf16x8*)(qkv_wb + row * CDIM + c0 + quad * 8);
                } else {
                    const float* ap = qkv_w + row * CDIM + c0 + quad * 8;
                    f32x4 a0 = *(const f32x4*)ap;
                    f32x4 a1 = *(const f32x4*)(ap + 4);
                    bf16x8 t;
                    #pragma unroll
                    for (int j = 0; j < 4; ++j) { t[j] = (bf16_t)a0[j]; t[j+4] = (bf16_t)a1[j]; }
                    afr[rtl] = t;
                }
            }
            bf16x8 bfr[4];
            #pragma unroll
            for (int ct = 0; ct < 4; ++ct)
                bfr[ct] = *(const bf16x8*)(xs + (ct * 16 + l15) * 264 + c0 + quad * 8);
            #pragma unroll
            for (int rtl = 0; rtl < 2; ++rtl)
                #pragma unroll
                for (int ct = 0; ct < 4; ++ct)
                    acc[rtl][ct] = mfma16(afr[rtl], bfr[ct], acc[rtl][ct]);
        }
        #pragma unroll
        for (int rtl = 0; rtl < 2; ++rtl) {
            f32x4 b4 = *(const f32x4*)(qkv_b + sec * 256 + h * 32 + rtl * 16 + quad * 4);
            #pragma unroll
            for (int ct = 0; ct < 4; ++ct) {
                #pragma unroll
                for (int r = 0; r < 4; ++r) {
                    float vv = acc[rtl][ct][r] + b4[r];
                    if (sec == 0) qpk[rtl][ct][r] = (bf16_t)(vv * scale);
                    else          kpk[rtl][ct][r] = (bf16_t)vv;
                }
            }
        }
    }
    {   // V pass (swapped operands: m on quad/reg, d on lanes)
        f32x4 acc[4][2];
        #pragma unroll
        for (int ct = 0; ct < 4; ++ct)
            #pragma unroll
            for (int rtl = 0; rtl < 2; ++rtl) acc[ct][rtl] = (f32x4){0.f,0.f,0.f,0.f};

        #pragma unroll 1
        for (int kk = 0; kk < 8; ++kk) {
            const int c0 = kk * 32;
            bf16x8 afr[2];
            #pragma unroll
            for (int rtl = 0; rtl < 2; ++rtl) {
                int row = 512 + h * 32 + rtl * 16 + l15;
                if constexpr (USE_WS) {
                    afr[rtl] = *(const bf16x8*)(qkv_wb + row * CDIM + c0 + quad * 8);
                } else {
                    const float* ap = qkv_w + row * CDIM + c0 + quad * 8;
                    f32x4 a0 = *(const f32x4*)ap;
                    f32x4 a1 = *(const f32x4*)(ap + 4);
                    bf16x8 t;
                    #pragma unroll
                    for (int j = 0; j < 4; ++j) { t[j] = (bf16_t)a0[j]; t[j+4] = (bf16_t)a1[j]; }
                    afr[rtl] = t;
                }
            }
            bf16x8 bfr[4];
            #pragma unroll
            for (int ct = 0; ct < 4; ++ct)
                bfr[ct] = *(const bf16x8*)(xs + (ct * 16 + l15) * 264 + c0 + quad * 8);
            #pragma unroll
            for (int ct = 0; ct < 4; ++ct)
                #pragma unroll
                for (int rtl = 0; rtl < 2; ++rtl)
                    acc[ct][rtl] = mfma16(bfr[ct], afr[rtl], acc[ct][rtl]);
        }
        #pragma unroll
        for (int rtl = 0; rtl < 2; ++rtl) {
            float bv = qkv_b[512 + h * 32 + rtl * 16 + l15];
            #pragma unroll
            for (int ct = 0; ct < 4; ++ct)
                #pragma unroll
                for (int r = 0; r < 4; ++r) vpk[ct][rtl][r] = (bf16_t)(acc[ct][rtl][r] + bv);
        }
    }
    __syncthreads();   // xs dead; region0 becomes per-wave scratch

    // ---- Q -> buf0 [64][40] from packed regs, read qa fragments
    #pragma unroll
    for (int rtl = 0; rtl < 2; ++rtl)
        #pragma unroll
        for (int ct = 0; ct < 4; ++ct)
            *(bf16x4*)(buf0 + (ct * 16 + l15) * 40 + rtl * 16 + quad * 4) = qpk[rtl][ct];
    bf16x8 qa[4];
    #pragma unroll
    for (int nt = 0; nt < 4; ++nt)
        qa[nt] = *(const bf16x8*)(buf0 + (nt * 16 + l15) * 40 + quad * 8);

    // ---- K -> buf0 (overwrite), read kb fragments
    #pragma unroll
    for (int rtl = 0; rtl < 2; ++rtl)
        #pragma unroll
        for (int ct = 0; ct < 4; ++ct)
            *(bf16x4*)(buf0 + (ct * 16 + l15) * 40 + rtl * 16 + quad * 4) = kpk[rtl][ct];
    bf16x8 kb[4];
    #pragma unroll
    for (int mt = 0; mt < 4; ++mt)
        kb[mt] = *(const bf16x8*)(buf0 + (mt * 16 + l15) * 40 + quad * 8);

    // ---- V -> buf0 as [32][72] from packed regs (vectorized along m)
    #pragma unroll
    for (int rtl = 0; rtl < 2; ++rtl)
        #pragma unroll
        for (int ct = 0; ct < 4; ++ct)
            *(bf16x4*)(buf0 + (rtl * 16 + l15) * 72 + ct * 16 + quad * 4) = vpk[ct][rtl];

    // ---- S^T + softmax fused per column nt: only 4 f32x4 S-regs live at a time.
    //      S^T = mfma(kb, qa): m on (quad,reg), n on lanes.
    float inv[4];
    bf16x4 ppk[4][4];   // [mt][nt]
    {
        const int qhi = quad >> 1, qlo = quad & 1;
        const int nwv = (l15 & 7) + 7 - 4 * qlo;   // (nw - mw0 + 7)
        const int nh_ = l15 >> 3;
        #pragma unroll
        for (int nt = 0; nt < 4; ++nt) {
            f32x4 scol[4];
            #pragma unroll
            for (int mt = 0; mt < 4; ++mt)
                scol[mt] = mfma16(kb[mt], qa[nt], (f32x4){0.f,0.f,0.f,0.f});
            const int n = nt * 16 + l15;
            #pragma unroll
            for (int mt = 0; mt < 4; ++mt) {
                f32x4 mv = *(const f32x4*)(mask_lds + n * 68 + mt * 16 + quad * 4);
                int base = (nt * 2 + nh_ - 2 * mt - qhi + 7) * 15 + nwv;
                #pragma unroll
                for (int r = 0; r < 4; ++r)
                    scol[mt][r] += bias_table[(base - r) * NH + h] + mv[r];
            }
            float mx = scol[0][0];
            #pragma unroll
            for (int mt = 0; mt < 4; ++mt)
                #pragma unroll
                for (int r = 0; r < 4; ++r) mx = fmaxf(mx, scol[mt][r]);
            mx = fmaxf(mx, __shfl_xor(mx, 16, 64));
            mx = fmaxf(mx, __shfl_xor(mx, 32, 64));
            float s = 0.f;
            #pragma unroll
            for (int mt = 0; mt < 4; ++mt)
                #pragma unroll
                for (int r = 0; r < 4; ++r) {
                    float e = __expf(scol[mt][r] - mx);
                    ppk[mt][nt][r] = (bf16_t)e;
                    s += e;
                }
            s += __shfl_xor(s, 16, 64);
            s += __shfl_xor(s, 32, 64);
            inv[nt] = __builtin_amdgcn_rcpf(s);
        }
    }

    // ---- PV: read vb (before P overwrites V region!), then P halves through buf0.
    bf16x8 vb[2][2];
    #pragma unroll
    for (int dt = 0; dt < 2; ++dt)
        #pragma unroll
        for (int ch = 0; ch < 2; ++ch)
            vb[dt][ch] = *(const bf16x8*)(buf0 + (dt * 16 + l15) * 72 + ch * 32 + quad * 8);

    f32x4 oaccT[2][4];   // [dt][nt]: d on (quad,reg), n on lanes
    #pragma unroll
    for (int dt = 0; dt < 2; ++dt)
        #pragma unroll
        for (int nt = 0; nt < 4; ++nt) oaccT[dt][nt] = (f32x4){0.f,0.f,0.f,0.f};

    #pragma unroll
    for (int ch = 0; ch < 2; ++ch) {
        #pragma unroll
        for (int mt2 = 0; mt2 < 2; ++mt2) {   // mt = 2*ch + mt2
            #pragma unroll
            for (int nt = 0; nt < 4; ++nt)
                *(bf16x4*)(buf0 + (nt * 16 + l15) * 40 + mt2 * 16 + quad * 4) = ppk[2 * ch + mt2][nt];
        }
        #pragma unroll
        for (int nt = 0; nt < 4; ++nt) {
            bf16x8 pb = *(const bf16x8*)(buf0 + (nt * 16 + l15) * 40 + quad * 8);
            #pragma unroll
            for (int dt = 0; dt < 2; ++dt)
                oaccT[dt][nt] = mfma16(vb[dt][ch], pb, oaccT[dt][nt]);
        }
    }
    __syncthreads();   // all waves done with scratch; region0 becomes o_lds

    // ---- Phase 6: O -> o_lds[n][c] (normalize by inv here; vectorized bf16x4 along c)
    #pragma unroll
    for (int dt = 0; dt < 2; ++dt)
        #pragma unroll
        for (int nt = 0; nt < 4; ++nt) {
            bf16x4 pk;
            #pragma unroll
            for (int r = 0; r < 4; ++r) pk[r] = (bf16_t)(oaccT[dt][nt][r] * inv[nt]);
            *(bf16x4*)(o_lds + (nt * 16 + l15) * 264 + h * 32 + dt * 16 + quad * 4) = pk;
        }
    __syncthreads();

    // ---- Phase 7: Y^T[e][n] = proj_w(e,:) . O(n,:); wave w -> e in [w*32, w*32+32)
    {
        f32x4 yacc[2][4];
        #pragma unroll
        for (int rt = 0; rt < 2; ++rt)
            #pragma unroll
            for (int ct = 0; ct < 4; ++ct) yacc[rt][ct] = (f32x4){0.f,0.f,0.f,0.f};

        #pragma unroll 1
        for (int kk = 0; kk < 8; ++kk) {
            const int c0 = kk * 32;
            bf16x8 afr[2];
            #pragma unroll
            for (int rt = 0; rt < 2; ++rt) {
                int e = w * 32 + rt * 16 + l15;
                if constexpr (USE_WS) {
                    afr[rt] = *(const bf16x8*)(proj_wb + e * CDIM + c0 + quad * 8);
                } else {
                    const float* ap = proj_w + e * CDIM + c0 + quad * 8;
                    f32x4 a0 = *(const f32x4*)ap;
                    f32x4 a1 = *(const f32x4*)(ap + 4);
                    bf16x8 t;
                    #pragma unroll
                    for (int j = 0; j < 4; ++j) { t[j] = (bf16_t)a0[j]; t[j+4] = (bf16_t)a1[j]; }
                    afr[rt] = t;
                }
            }
            bf16x8 bfr[4];
            #pragma unroll
            for (int ct = 0; ct < 4; ++ct)
                bfr[ct] = *(const bf16x8*)(o_lds + (ct * 16 + l15) * 264 + c0 + quad * 8);
            #pragma unroll
            for (int rt = 0; rt < 2; ++rt)
                #pragma unroll
                for (int ct = 0; ct < 4; ++ct)
                    yacc[rt][ct] = mfma16(afr[rt], bfr[ct], yacc[rt][ct]);
        }
        float* ob = out + (size_t)b * (NTOK * CDIM);
        #pragma unroll
        for (int rt = 0; rt < 2; ++rt) {
            int e0 = w * 32 + rt * 16 + quad * 4;
            f32x4 pb4 = *(const f32x4*)(proj_b + e0);
            #pragma unroll
            for (int ct = 0; ct < 4; ++ct) {
                int n = ct * 16 + l15;
                f32x4 r = yacc[rt][ct] + pb4;
                *(f32x4*)(ob + n * 256 + e0) = r;
            }
        }
    }
}

// Convert fp32 weights to bf16 once per launch (into workspace).
__global__ void cvt_weights(const float* __restrict__ qkv_w,
                            const float* __restrict__ proj_w,
                            bf16_t* __restrict__ qkv_wb,
                            bf16_t* __restrict__ proj_wb)
{
    int i = blockIdx.x * 256 + threadIdx.x;
    int base = i * 4;
    const float* src; bf16_t* dst;
    if (base < 196608) { src = qkv_w + base; dst = qkv_wb + base; }
    else { base -= 196608; src = proj_w + base; dst = proj_wb + base; }
    f32x4 v = *(const f32x4*)src;
    bf16x4 o;
    #pragma unroll
    for (int j = 0; j < 4; ++j) o[j] = (bf16_t)v[j];
    *(bf16x4*)dst = o;
}

extern "C" void kernel_launch(void* const* d_in, const int* in_sizes, int n_in,
                              void* d_out, int out_size, void* d_ws, size_t ws_size,
                              hipStream_t stream) {
    const float* x          = (const float*)d_in[0];
    const float* mask       = (const float*)d_in[1];
    const float* qkv_w      = (const float*)d_in[2];
    const float* qkv_b      = (const float*)d_in[3];
    const float* proj_w     = (const float*)d_in[4];
    const float* proj_b     = (const float*)d_in[5];
    const float* bias_table = (const float*)d_in[6];
    float* out = (float*)d_out;

    const size_t ws_needed = (size_t)(196608 + 65536) * sizeof(bf16_t);  // 524288 B
    if (ws_size >= ws_needed) {
        bf16_t* qkv_wb  = (bf16_t*)d_ws;
        bf16_t* proj_wb = qkv_wb + 196608;
        cvt_weights<<<256, 256, 0, stream>>>(qkv_w, proj_w, qkv_wb, proj_wb);
        win_attn_kernel<true><<<NWIN, 512, 0, stream>>>(
            x, mask, qkv_w, qkv_b, proj_w, proj_b, bias_table, qkv_wb, proj_wb, out);
    } else {
        win_attn_kernel<false><<<NWIN, 512, 0, stream>>>(
            x, mask, qkv_w, qkv_b, proj_w, proj_b, bias_table, nullptr, nullptr, out);
    }
}

// Round 5
// 747.626 us; speedup vs baseline: 1.8970x; 1.0680x over previous
//
#include <hip/hip_runtime.h>

typedef __bf16 bf16_t;
typedef bf16_t bf16x8 __attribute__((ext_vector_type(8)));
typedef bf16_t bf16x4 __attribute__((ext_vector_type(4)));
typedef float  f32x4  __attribute__((ext_vector_type(4)));

#define NWIN 4096
#define CDIM 256
#define NTOK 64
#define NH   8

// LDS (58368 B total; 2 blocks/CU):
//  region0 [0, 40960) — time-shared:
//    phase 1-2 : xs [64][264] bf16 (x^T staged, row pad 264) = 33792 B
//    attention : per-wave scratch buf0 = region0 + w*5120 (5120 B each):
//                Q [64][40] -> K [64][40] -> V [32][72] -> P-halves [64][40]
//    phase 6-7 : o_lds [64][264] bf16 = 33792 B
//  mask [40960, 58368): mask [64][68] f32 (row pad 68 -> 2-way on column reads)
#define OFF_MASK  40960
#define LDS_BYTES 58368

__device__ __forceinline__ f32x4 mfma16(bf16x8 a, bf16x8 b, f32x4 c) {
    return __builtin_amdgcn_mfma_f32_16x16x32_bf16(a, b, c, 0, 0, 0);
}

// Load one 8-wide bf16 weight fragment (row-major [*, CDIM]); c includes quad*8.
template<bool USE_WS>
__device__ __forceinline__ bf16x8 load_wrow(const bf16_t* wb, const float* wf, int row, int c) {
    if constexpr (USE_WS) {
        return *(const bf16x8*)(wb + row * CDIM + c);
    } else {
        const float* ap = wf + row * CDIM + c;
        f32x4 a0 = *(const f32x4*)ap;
        f32x4 a1 = *(const f32x4*)(ap + 4);
        bf16x8 t;
        #pragma unroll
        for (int j = 0; j < 4; ++j) { t[j] = (bf16_t)a0[j]; t[j + 4] = (bf16_t)a1[j]; }
        return t;
    }
}

template<bool USE_WS>
__launch_bounds__(512, 4)
__global__ void win_attn_kernel(const float* __restrict__ x,
                                const float* __restrict__ mask,
                                const float* __restrict__ qkv_w,
                                const float* __restrict__ qkv_b,
                                const float* __restrict__ proj_w,
                                const float* __restrict__ proj_b,
                                const float* __restrict__ bias_table,
                                const bf16_t* __restrict__ qkv_wb,
                                const bf16_t* __restrict__ proj_wb,
                                const float* __restrict__ bias_pre,
                                float* __restrict__ out)
{
    __shared__ __attribute__((aligned(16))) unsigned char smem[LDS_BYTES];
    bf16_t* xs       = (bf16_t*)smem;            // phase 1-2
    bf16_t* o_lds    = (bf16_t*)smem;            // phase 6-7
    float*  mask_lds = (float*)(smem + OFF_MASK);

    const int b    = blockIdx.x;
    const int tid  = threadIdx.x;
    const int w    = tid >> 6;        // wave id == head id
    const int lane = tid & 63;
    const int quad = lane >> 4;
    const int l15  = lane & 15;
    bf16_t* buf0 = (bf16_t*)(smem + w * 5120);   // per-wave scratch (attention)

    // ---- Phase 1: stage x[b] ([256][64] f32 -> xs[n][c] bf16) + mask (padded f32)
    {
        const float* xb = x + (size_t)b * (CDIM * NTOK);
        #pragma unroll
        for (int cb = 0; cb < 4; ++cb) {
            const int c0 = cb * 64 + w * 8;
            float v[8];
            #pragma unroll
            for (int j = 0; j < 8; ++j) v[j] = xb[(c0 + j) * 64 + lane];  // coalesced dwords
            bf16x8 t;
            #pragma unroll
            for (int j = 0; j < 8; ++j) t[j] = (bf16_t)v[j];
            *(bf16x8*)(xs + lane * 264 + c0) = t;                          // b128, 2-way
        }
        const float* mb = mask + (size_t)b * (NTOK * NTOK);
        #pragma unroll
        for (int it = 0; it < 2; ++it) {
            int e = (it * 512 + tid) * 4;
            int n = e >> 6, m = e & 63;
            f32x4 mv = *(const f32x4*)(mb + e);
            *(f32x4*)(mask_lds + n * 68 + m) = mv;
        }
    }
    __syncthreads();

    const int h = w;
    const float scale = 0.17677669529663687f;

    // ---- Phase 2: per-head QKV, passes ordered V -> K -> Q.
    //      V,K results pack+bias to bf16 regs (16 each). Q stays in its 32
    //      accumulators and is written to LDS directly after the barrier
    //      (xs dead then) — keeps peak live regs ~111, no spills.
    //      Weight fragments prefetch-rotated one K-step ahead.
    bf16x4 kpk[2][4];  // k[d=rtl*16+quad*4+r][n=ct*16+l15]
    bf16x4 vpk[4][2];  // v[m=ct*16+quad*4+r][d=rtl*16+l15] (swapped orientation)

    {   // V pass (swapped operands: m on quad/reg, d on lanes)
        f32x4 acc[4][2];
        #pragma unroll
        for (int ct = 0; ct < 4; ++ct)
            #pragma unroll
            for (int rtl = 0; rtl < 2; ++rtl) acc[ct][rtl] = (f32x4){0.f,0.f,0.f,0.f};

        const int r0 = 512 + h * 32 + l15;
        bf16x8 a0 = load_wrow<USE_WS>(qkv_wb, qkv_w, r0,      quad * 8);
        bf16x8 a1 = load_wrow<USE_WS>(qkv_wb, qkv_w, r0 + 16, quad * 8);
        #pragma unroll 1
        for (int kk = 0; kk < 8; ++kk) {
            const int c0 = kk * 32;
            const int c1 = ((kk + 1) & 7) * 32 + quad * 8;
            bf16x8 n0 = load_wrow<USE_WS>(qkv_wb, qkv_w, r0,      c1);
            bf16x8 n1 = load_wrow<USE_WS>(qkv_wb, qkv_w, r0 + 16, c1);
            bf16x8 bfr[4];
            #pragma unroll
            for (int ct = 0; ct < 4; ++ct)
                bfr[ct] = *(const bf16x8*)(xs + (ct * 16 + l15) * 264 + c0 + quad * 8);
            #pragma unroll
            for (int ct = 0; ct < 4; ++ct) {
                acc[ct][0] = mfma16(bfr[ct], a0, acc[ct][0]);
                acc[ct][1] = mfma16(bfr[ct], a1, acc[ct][1]);
            }
            a0 = n0; a1 = n1;
        }
        #pragma unroll
        for (int rtl = 0; rtl < 2; ++rtl) {
            float bv = qkv_b[512 + h * 32 + rtl * 16 + l15];
            #pragma unroll
            for (int ct = 0; ct < 4; ++ct)
                #pragma unroll
                for (int r = 0; r < 4; ++r) vpk[ct][rtl][r] = (bf16_t)(acc[ct][rtl][r] + bv);
        }
    }
    {   // K pass (d on quad/reg, n on lanes)
        f32x4 acc[2][4];
        #pragma unroll
        for (int rtl = 0; rtl < 2; ++rtl)
            #pragma unroll
            for (int ct = 0; ct < 4; ++ct) acc[rtl][ct] = (f32x4){0.f,0.f,0.f,0.f};

        const int r0 = 256 + h * 32 + l15;
        bf16x8 a0 = load_wrow<USE_WS>(qkv_wb, qkv_w, r0,      quad * 8);
        bf16x8 a1 = load_wrow<USE_WS>(qkv_wb, qkv_w, r0 + 16, quad * 8);
        #pragma unroll 1
        for (int kk = 0; kk < 8; ++kk) {
            const int c0 = kk * 32;
            const int c1 = ((kk + 1) & 7) * 32 + quad * 8;
            bf16x8 n0 = load_wrow<USE_WS>(qkv_wb, qkv_w, r0,      c1);
            bf16x8 n1 = load_wrow<USE_WS>(qkv_wb, qkv_w, r0 + 16, c1);
            bf16x8 bfr[4];
            #pragma unroll
            for (int ct = 0; ct < 4; ++ct)
                bfr[ct] = *(const bf16x8*)(xs + (ct * 16 + l15) * 264 + c0 + quad * 8);
            #pragma unroll
            for (int ct = 0; ct < 4; ++ct) {
                acc[0][ct] = mfma16(a0, bfr[ct], acc[0][ct]);
                acc[1][ct] = mfma16(a1, bfr[ct], acc[1][ct]);
            }
            a0 = n0; a1 = n1;
        }
        #pragma unroll
        for (int rtl = 0; rtl < 2; ++rtl) {
            f32x4 b4 = *(const f32x4*)(qkv_b + 256 + h * 32 + rtl * 16 + quad * 4);
            #pragma unroll
            for (int ct = 0; ct < 4; ++ct)
                #pragma unroll
                for (int r = 0; r < 4; ++r) kpk[rtl][ct][r] = (bf16_t)(acc[rtl][ct][r] + b4[r]);
        }
    }
    // Q pass (accumulators stay live across the barrier; no packing)
    f32x4 qacc[2][4];
    {
        #pragma unroll
        for (int rtl = 0; rtl < 2; ++rtl)
            #pragma unroll
            for (int ct = 0; ct < 4; ++ct) qacc[rtl][ct] = (f32x4){0.f,0.f,0.f,0.f};

        const int r0 = h * 32 + l15;
        bf16x8 a0 = load_wrow<USE_WS>(qkv_wb, qkv_w, r0,      quad * 8);
        bf16x8 a1 = load_wrow<USE_WS>(qkv_wb, qkv_w, r0 + 16, quad * 8);
        #pragma unroll 1
        for (int kk = 0; kk < 8; ++kk) {
            const int c0 = kk * 32;
            const int c1 = ((kk + 1) & 7) * 32 + quad * 8;
            bf16x8 n0 = load_wrow<USE_WS>(qkv_wb, qkv_w, r0,      c1);
            bf16x8 n1 = load_wrow<USE_WS>(qkv_wb, qkv_w, r0 + 16, c1);
            bf16x8 bfr[4];
            #pragma unroll
            for (int ct = 0; ct < 4; ++ct)
                bfr[ct] = *(const bf16x8*)(xs + (ct * 16 + l15) * 264 + c0 + quad * 8);
            #pragma unroll
            for (int ct = 0; ct < 4; ++ct) {
                qacc[0][ct] = mfma16(a0, bfr[ct], qacc[0][ct]);
                qacc[1][ct] = mfma16(a1, bfr[ct], qacc[1][ct]);
            }
            a0 = n0; a1 = n1;
        }
    }
    __syncthreads();   // xs dead; region0 becomes per-wave scratch

    // ---- Q -> buf0 [64][40] straight from accumulators (+bias, *scale)
    #pragma unroll
    for (int rtl = 0; rtl < 2; ++rtl) {
        f32x4 b4 = *(const f32x4*)(qkv_b + h * 32 + rtl * 16 + quad * 4);
        #pragma unroll
        for (int ct = 0; ct < 4; ++ct) {
            bf16x4 pk;
            #pragma unroll
            for (int r = 0; r < 4; ++r) pk[r] = (bf16_t)((qacc[rtl][ct][r] + b4[r]) * scale);
            *(bf16x4*)(buf0 + (ct * 16 + l15) * 40 + rtl * 16 + quad * 4) = pk;
        }
    }
    bf16x8 qa[4];
    #pragma unroll
    for (int nt = 0; nt < 4; ++nt)
        qa[nt] = *(const bf16x8*)(buf0 + (nt * 16 + l15) * 40 + quad * 8);

    // ---- K -> buf0 (overwrite), read kb fragments
    #pragma unroll
    for (int rtl = 0; rtl < 2; ++rtl)
        #pragma unroll
        for (int ct = 0; ct < 4; ++ct)
            *(bf16x4*)(buf0 + (ct * 16 + l15) * 40 + rtl * 16 + quad * 4) = kpk[rtl][ct];
    bf16x8 kb[4];
    #pragma unroll
    for (int mt = 0; mt < 4; ++mt)
        kb[mt] = *(const bf16x8*)(buf0 + (mt * 16 + l15) * 40 + quad * 8);

    // ---- V -> buf0 as [32][72] from packed regs (vectorized along m)
    #pragma unroll
    for (int rtl = 0; rtl < 2; ++rtl)
        #pragma unroll
        for (int ct = 0; ct < 4; ++ct)
            *(bf16x4*)(buf0 + (rtl * 16 + l15) * 72 + ct * 16 + quad * 4) = vpk[ct][rtl];

    // ---- S^T + softmax fused per column nt: only 4 f32x4 S-regs live at a time.
    //      S^T = mfma(kb, qa): m on (quad,reg), n on lanes.
    float inv[4];
    bf16x4 ppk[4][4];   // [mt][nt]
    {
        const int qhi = quad >> 1, qlo = quad & 1;
        const int nwv = (l15 & 7) + 7 - 4 * qlo;   // (nw - mw0 + 7)
        const int nh_ = l15 >> 3;
        #pragma unroll
        for (int nt = 0; nt < 4; ++nt) {
            f32x4 scol[4];
            #pragma unroll
            for (int mt = 0; mt < 4; ++mt)
                scol[mt] = mfma16(kb[mt], qa[nt], (f32x4){0.f,0.f,0.f,0.f});
            const int n = nt * 16 + l15;
            if constexpr (USE_WS) {
                const float* bh = bias_pre + (h << 12) + n * 64;
                #pragma unroll
                for (int mt = 0; mt < 4; ++mt) {
                    f32x4 bv = *(const f32x4*)(bh + mt * 16 + quad * 4);
                    f32x4 mv = *(const f32x4*)(mask_lds + n * 68 + mt * 16 + quad * 4);
                    scol[mt] += bv + mv;
                }
            } else {
                #pragma unroll
                for (int mt = 0; mt < 4; ++mt) {
                    f32x4 mv = *(const f32x4*)(mask_lds + n * 68 + mt * 16 + quad * 4);
                    int base = (nt * 2 + nh_ - 2 * mt - qhi + 7) * 15 + nwv;
                    #pragma unroll
                    for (int r = 0; r < 4; ++r)
                        scol[mt][r] += bias_table[(base - r) * NH + h] + mv[r];
                }
            }
            float mx = scol[0][0];
            #pragma unroll
            for (int mt = 0; mt < 4; ++mt)
                #pragma unroll
                for (int r = 0; r < 4; ++r) mx = fmaxf(mx, scol[mt][r]);
            mx = fmaxf(mx, __shfl_xor(mx, 16, 64));
            mx = fmaxf(mx, __shfl_xor(mx, 32, 64));
            float s = 0.f;
            #pragma unroll
            for (int mt = 0; mt < 4; ++mt)
                #pragma unroll
                for (int r = 0; r < 4; ++r) {
                    float e = __expf(scol[mt][r] - mx);
                    ppk[mt][nt][r] = (bf16_t)e;
                    s += e;
                }
            s += __shfl_xor(s, 16, 64);
            s += __shfl_xor(s, 32, 64);
            inv[nt] = __builtin_amdgcn_rcpf(s);
        }
    }

    // ---- PV: read vb (before P overwrites V region!), then P halves through buf0.
    bf16x8 vb[2][2];
    #pragma unroll
    for (int dt = 0; dt < 2; ++dt)
        #pragma unroll
        for (int ch = 0; ch < 2; ++ch)
            vb[dt][ch] = *(const bf16x8*)(buf0 + (dt * 16 + l15) * 72 + ch * 32 + quad * 8);

    f32x4 oaccT[2][4];   // [dt][nt]: d on (quad,reg), n on lanes
    #pragma unroll
    for (int dt = 0; dt < 2; ++dt)
        #pragma unroll
        for (int nt = 0; nt < 4; ++nt) oaccT[dt][nt] = (f32x4){0.f,0.f,0.f,0.f};

    #pragma unroll
    for (int ch = 0; ch < 2; ++ch) {
        #pragma unroll
        for (int mt2 = 0; mt2 < 2; ++mt2) {   // mt = 2*ch + mt2
            #pragma unroll
            for (int nt = 0; nt < 4; ++nt)
                *(bf16x4*)(buf0 + (nt * 16 + l15) * 40 + mt2 * 16 + quad * 4) = ppk[2 * ch + mt2][nt];
        }
        #pragma unroll
        for (int nt = 0; nt < 4; ++nt) {
            bf16x8 pb = *(const bf16x8*)(buf0 + (nt * 16 + l15) * 40 + quad * 8);
            #pragma unroll
            for (int dt = 0; dt < 2; ++dt)
                oaccT[dt][nt] = mfma16(vb[dt][ch], pb, oaccT[dt][nt]);
        }
    }
    __syncthreads();   // all waves done with scratch; region0 becomes o_lds

    // ---- Phase 6: O -> o_lds[n][c] (normalize by inv here; vectorized bf16x4 along c)
    #pragma unroll
    for (int dt = 0; dt < 2; ++dt)
        #pragma unroll
        for (int nt = 0; nt < 4; ++nt) {
            bf16x4 pk;
            #pragma unroll
            for (int r = 0; r < 4; ++r) pk[r] = (bf16_t)(oaccT[dt][nt][r] * inv[nt]);
            *(bf16x4*)(o_lds + (nt * 16 + l15) * 264 + h * 32 + dt * 16 + quad * 4) = pk;
        }
    __syncthreads();

    // ---- Phase 7: Y^T[e][n] = proj_w(e,:) . O(n,:); wave w -> e in [w*32, w*32+32)
    {
        f32x4 yacc[2][4];
        #pragma unroll
        for (int rt = 0; rt < 2; ++rt)
            #pragma unroll
            for (int ct = 0; ct < 4; ++ct) yacc[rt][ct] = (f32x4){0.f,0.f,0.f,0.f};

        const int e0r = w * 32 + l15;
        bf16x8 a0 = load_wrow<USE_WS>(proj_wb, proj_w, e0r,      quad * 8);
        bf16x8 a1 = load_wrow<USE_WS>(proj_wb, proj_w, e0r + 16, quad * 8);
        #pragma unroll 1
        for (int kk = 0; kk < 8; ++kk) {
            const int c0 = kk * 32;
            const int c1 = ((kk + 1) & 7) * 32 + quad * 8;
            bf16x8 n0 = load_wrow<USE_WS>(proj_wb, proj_w, e0r,      c1);
            bf16x8 n1 = load_wrow<USE_WS>(proj_wb, proj_w, e0r + 16, c1);
            bf16x8 bfr[4];
            #pragma unroll
            for (int ct = 0; ct < 4; ++ct)
                bfr[ct] = *(const bf16x8*)(o_lds + (ct * 16 + l15) * 264 + c0 + quad * 8);
            #pragma unroll
            for (int ct = 0; ct < 4; ++ct) {
                yacc[0][ct] = mfma16(a0, bfr[ct], yacc[0][ct]);
                yacc[1][ct] = mfma16(a1, bfr[ct], yacc[1][ct]);
            }
            a0 = n0; a1 = n1;
        }
        float* ob = out + (size_t)b * (NTOK * CDIM);
        #pragma unroll
        for (int rt = 0; rt < 2; ++rt) {
            int e0 = w * 32 + rt * 16 + quad * 4;
            f32x4 pb4 = *(const f32x4*)(proj_b + e0);
            #pragma unroll
            for (int ct = 0; ct < 4; ++ct) {
                int n = ct * 16 + l15;
                f32x4 r = yacc[rt][ct] + pb4;
                *(f32x4*)(ob + n * 256 + e0) = r;
            }
        }
    }
}

// One-time: fp32 weights -> bf16 workspace, plus bias_pre[h][n][m] f32 table.
__global__ void cvt_weights(const float* __restrict__ qkv_w,
                            const float* __restrict__ proj_w,
                            const float* __restrict__ bias_table,
                            bf16_t* __restrict__ qkv_wb,
                            bf16_t* __restrict__ proj_wb,
                            float* __restrict__ bias_pre)
{
    int i = blockIdx.x * 256 + threadIdx.x;
    if (i < 65536) {
        int base = i * 4;
        const float* src; bf16_t* dst;
        if (base < 196608) { src = qkv_w + base; dst = qkv_wb + base; }
        else { base -= 196608; src = proj_w + base; dst = proj_wb + base; }
        f32x4 v = *(const f32x4*)src;
        bf16x4 o;
        #pragma unroll
        for (int j = 0; j < 4; ++j) o[j] = (bf16_t)v[j];
        *(bf16x4*)dst = o;
    } else {
        int base = (i - 65536) * 4;          // index into [8][64][64]
        int h = base >> 12, n = (base >> 6) & 63, m0 = base & 63;
        f32x4 o;
        #pragma unroll
        for (int j = 0; j < 4; ++j) {
            int m = m0 + j;
            int idx = ((n >> 3) - (m >> 3) + 7) * 15 + ((n & 7) - (m & 7) + 7);
            o[j] = bias_table[idx * NH + h];
        }
        *(f32x4*)(bias_pre + base) = o;
    }
}

extern "C" void kernel_launch(void* const* d_in, const int* in_sizes, int n_in,
                              void* d_out, int out_size, void* d_ws, size_t ws_size,
                              hipStream_t stream) {
    const float* x          = (const float*)d_in[0];
    const float* mask       = (const float*)d_in[1];
    const float* qkv_w      = (const float*)d_in[2];
    const float* qkv_b      = (const float*)d_in[3];
    const float* proj_w     = (const float*)d_in[4];
    const float* proj_b     = (const float*)d_in[5];
    const float* bias_table = (const float*)d_in[6];
    float* out = (float*)d_out;

    const size_t ws_needed = 524288 + 524288;   // bf16 weights + f32 bias_pre
    if (ws_size >= ws_needed) {
        bf16_t* qkv_wb  = (bf16_t*)d_ws;
        bf16_t* proj_wb = qkv_wb + 196608;
        float*  bias_pre = (float*)((unsigned char*)d_ws + 524288);
        cvt_weights<<<384, 256, 0, stream>>>(qkv_w, proj_w, bias_table, qkv_wb, proj_wb, bias_pre);
        win_attn_kernel<true><<<NWIN, 512, 0, stream>>>(
            x, mask, qkv_w, qkv_b, proj_w, proj_b, bias_table, qkv_wb, proj_wb, bias_pre, out);
    } else {
        win_attn_kernel<false><<<NWIN, 512, 0, stream>>>(
            x, mask, qkv_w, qkv_b, proj_w, proj_b, bias_table, nullptr, nullptr, nullptr, out);
    }
}

// Round 6
// 733.480 us; speedup vs baseline: 1.9336x; 1.0193x over previous
//
#include <hip/hip_runtime.h>

typedef __bf16 bf16_t;
typedef bf16_t bf16x8 __attribute__((ext_vector_type(8)));
typedef bf16_t bf16x4 __attribute__((ext_vector_type(4)));
typedef float  f32x4  __attribute__((ext_vector_type(4)));

#define NWIN 4096
#define CDIM 256
#define NTOK 64
#define NH   8

// LDS 81920 B = exactly 2 blocks/CU (163840 total). All tiles unpadded + XOR-swizzled:
//  region0 [0, 32768) — time-shared:
//    phase 1-2 : xs [64][256] bf16, row-swizzle ^((row&7)<<4) on byte offset
//    attention : per-wave buf0 = region0 + w*4096:
//                Q [64][32]sw2 -> V [32][64]sw3 -> P [64][32]sw2 (time-shared)
//    phase 6-7 : o_lds [64][256] bf16, same swizzle as xs
//  kst  [32768, 65536): per-wave K [64][32] bf16, ^((row&3)<<4)   (written at K-pass
//                       epilogue, read at S^T by the same wave — no barrier needed)
//  mask [65536, 81920): [64][64] f32, ^((n&7)<<4)
#define OFF_KST  32768
#define OFF_MASK 65536
#define LDS_BYTES 81920

__device__ __forceinline__ f32x4 mfma16(bf16x8 a, bf16x8 b, f32x4 c) {
    return __builtin_amdgcn_mfma_f32_16x16x32_bf16(a, b, c, 0, 0, 0);
}

// Load one 8-wide bf16 weight fragment (row-major [*, CDIM]); c includes quad*8.
template<bool USE_WS>
__device__ __forceinline__ bf16x8 load_wrow(const bf16_t* wb, const float* wf, int row, int c) {
    if constexpr (USE_WS) {
        return *(const bf16x8*)(wb + row * CDIM + c);
    } else {
        const float* ap = wf + row * CDIM + c;
        f32x4 a0 = *(const f32x4*)ap;
        f32x4 a1 = *(const f32x4*)(ap + 4);
        bf16x8 t;
        #pragma unroll
        for (int j = 0; j < 4; ++j) { t[j] = (bf16_t)a0[j]; t[j + 4] = (bf16_t)a1[j]; }
        return t;
    }
}

template<bool USE_WS>
__launch_bounds__(512, 4)
__global__ void win_attn_kernel(const float* __restrict__ x,
                                const float* __restrict__ mask,
                                const float* __restrict__ qkv_w,
                                const float* __restrict__ qkv_b,
                                const float* __restrict__ proj_w,
                                const float* __restrict__ proj_b,
                                const float* __restrict__ bias_table,
                                const bf16_t* __restrict__ qkv_wb,
                                const bf16_t* __restrict__ proj_wb,
                                const float* __restrict__ bias_pre,
                                float* __restrict__ out)
{
    __shared__ __attribute__((aligned(16))) unsigned char smem[LDS_BYTES];

    const int b    = blockIdx.x;
    const int tid  = threadIdx.x;
    const int w    = tid >> 6;        // wave id == head id
    const int lane = tid & 63;
    const int quad = lane >> 4;
    const int l15  = lane & 15;
    unsigned char* buf0 = smem + w * 4096;              // per-wave scratch (Q/V/P)
    unsigned char* kst  = smem + OFF_KST + w * 4096;    // per-wave K staging

    // ---- Phase 1: stage x[b] ([256][64] f32 -> xs[n][c] bf16 swizzled) + mask
    {
        const float* xb = x + (size_t)b * (CDIM * NTOK);
        #pragma unroll
        for (int cb = 0; cb < 4; ++cb) {
            const int c0 = cb * 64 + w * 8;
            float v[8];
            #pragma unroll
            for (int j = 0; j < 8; ++j) v[j] = xb[(c0 + j) * 64 + lane];  // coalesced dwords
            bf16x8 t;
            #pragma unroll
            for (int j = 0; j < 8; ++j) t[j] = (bf16_t)v[j];
            *(bf16x8*)(smem + lane * 512 + ((c0 * 2) ^ ((lane & 7) << 4))) = t;
        }
        const float* mb = mask + (size_t)b * (NTOK * NTOK);
        #pragma unroll
        for (int it = 0; it < 2; ++it) {
            int e = (it * 512 + tid) * 4;
            int n = e >> 6, m = e & 63;
            f32x4 mv = *(const f32x4*)(mb + e);
            *(f32x4*)(smem + OFF_MASK + n * 256 + ((m * 4) ^ ((n & 7) << 4))) = mv;
        }
    }
    __syncthreads();

    const int h = w;
    const float scale = 0.17677669529663687f;

    // ---- Phase 2: per-head QKV, passes V -> K -> Q. 8 f32x4 acc per pass.
    //      V result -> 16 packed regs; K result -> kst LDS directly (no regs);
    //      Q stays in accumulators across the barrier. unroll-1 + weight prefetch.
    bf16x4 vpk[4][2];  // v[m=ct*16+quad*4+r][d=rtl*16+l15] (swapped orientation)

    {   // V pass (swapped operands: m on quad/reg, d on lanes)
        f32x4 acc[4][2];
        #pragma unroll
        for (int ct = 0; ct < 4; ++ct)
            #pragma unroll
            for (int rtl = 0; rtl < 2; ++rtl) acc[ct][rtl] = (f32x4){0.f,0.f,0.f,0.f};

        const int r0 = 512 + h * 32 + l15;
        bf16x8 a0 = load_wrow<USE_WS>(qkv_wb, qkv_w, r0,      quad * 8);
        bf16x8 a1 = load_wrow<USE_WS>(qkv_wb, qkv_w, r0 + 16, quad * 8);
        #pragma unroll 1
        for (int kk = 0; kk < 8; ++kk) {
            const int cb = kk * 64 + quad * 16;
            const int c1 = ((kk + 1) & 7) * 32 + quad * 8;
            bf16x8 n0 = load_wrow<USE_WS>(qkv_wb, qkv_w, r0,      c1);
            bf16x8 n1 = load_wrow<USE_WS>(qkv_wb, qkv_w, r0 + 16, c1);
            bf16x8 bfr[4];
            #pragma unroll
            for (int ct = 0; ct < 4; ++ct) {
                int row = ct * 16 + l15;
                bfr[ct] = *(const bf16x8*)(smem + row * 512 + (cb ^ ((row & 7) << 4)));
            }
            #pragma unroll
            for (int ct = 0; ct < 4; ++ct) {
                acc[ct][0] = mfma16(bfr[ct], a0, acc[ct][0]);
                acc[ct][1] = mfma16(bfr[ct], a1, acc[ct][1]);
            }
            a0 = n0; a1 = n1;
        }
        #pragma unroll
        for (int rtl = 0; rtl < 2; ++rtl) {
            float bv = qkv_b[512 + h * 32 + rtl * 16 + l15];
            #pragma unroll
            for (int ct = 0; ct < 4; ++ct)
                #pragma unroll
                for (int r = 0; r < 4; ++r) vpk[ct][rtl][r] = (bf16_t)(acc[ct][rtl][r] + bv);
        }
    }
    {   // K pass (d on quad/reg, n on lanes); epilogue writes straight to kst LDS
        f32x4 acc[2][4];
        #pragma unroll
        for (int rtl = 0; rtl < 2; ++rtl)
            #pragma unroll
            for (int ct = 0; ct < 4; ++ct) acc[rtl][ct] = (f32x4){0.f,0.f,0.f,0.f};

        const int r0 = 256 + h * 32 + l15;
        bf16x8 a0 = load_wrow<USE_WS>(qkv_wb, qkv_w, r0,      quad * 8);
        bf16x8 a1 = load_wrow<USE_WS>(qkv_wb, qkv_w, r0 + 16, quad * 8);
        #pragma unroll 1
        for (int kk = 0; kk < 8; ++kk) {
            const int cb = kk * 64 + quad * 16;
            const int c1 = ((kk + 1) & 7) * 32 + quad * 8;
            bf16x8 n0 = load_wrow<USE_WS>(qkv_wb, qkv_w, r0,      c1);
            bf16x8 n1 = load_wrow<USE_WS>(qkv_wb, qkv_w, r0 + 16, c1);
            bf16x8 bfr[4];
            #pragma unroll
            for (int ct = 0; ct < 4; ++ct) {
                int row = ct * 16 + l15;
                bfr[ct] = *(const bf16x8*)(smem + row * 512 + (cb ^ ((row & 7) << 4)));
            }
            #pragma unroll
            for (int ct = 0; ct < 4; ++ct) {
                acc[0][ct] = mfma16(a0, bfr[ct], acc[0][ct]);
                acc[1][ct] = mfma16(a1, bfr[ct], acc[1][ct]);
            }
            a0 = n0; a1 = n1;
        }
        #pragma unroll
        for (int rtl = 0; rtl < 2; ++rtl) {
            f32x4 b4 = *(const f32x4*)(qkv_b + 256 + h * 32 + rtl * 16 + quad * 4);
            #pragma unroll
            for (int ct = 0; ct < 4; ++ct) {
                bf16x4 pk;
                #pragma unroll
                for (int r = 0; r < 4; ++r) pk[r] = (bf16_t)(acc[rtl][ct][r] + b4[r]);
                int m = ct * 16 + l15;
                *(bf16x4*)(kst + m * 64 + ((rtl * 32 + quad * 8) ^ ((m & 3) << 4))) = pk;
            }
        }
    }
    // Q pass (accumulators stay live across the barrier; no packing)
    f32x4 qacc[2][4];
    {
        #pragma unroll
        for (int rtl = 0; rtl < 2; ++rtl)
            #pragma unroll
            for (int ct = 0; ct < 4; ++ct) qacc[rtl][ct] = (f32x4){0.f,0.f,0.f,0.f};

        const int r0 = h * 32 + l15;
        bf16x8 a0 = load_wrow<USE_WS>(qkv_wb, qkv_w, r0,      quad * 8);
        bf16x8 a1 = load_wrow<USE_WS>(qkv_wb, qkv_w, r0 + 16, quad * 8);
        #pragma unroll 1
        for (int kk = 0; kk < 8; ++kk) {
            const int cb = kk * 64 + quad * 16;
            const int c1 = ((kk + 1) & 7) * 32 + quad * 8;
            bf16x8 n0 = load_wrow<USE_WS>(qkv_wb, qkv_w, r0,      c1);
            bf16x8 n1 = load_wrow<USE_WS>(qkv_wb, qkv_w, r0 + 16, c1);
            bf16x8 bfr[4];
            #pragma unroll
            for (int ct = 0; ct < 4; ++ct) {
                int row = ct * 16 + l15;
                bfr[ct] = *(const bf16x8*)(smem + row * 512 + (cb ^ ((row & 7) << 4)));
            }
            #pragma unroll
            for (int ct = 0; ct < 4; ++ct) {
                qacc[0][ct] = mfma16(a0, bfr[ct], qacc[0][ct]);
                qacc[1][ct] = mfma16(a1, bfr[ct], qacc[1][ct]);
            }
            a0 = n0; a1 = n1;
        }
    }
    __syncthreads();   // xs dead; region0 becomes per-wave buf0

    // ---- Q -> buf0 [64][32]sw straight from accumulators (+bias, *scale)
    #pragma unroll
    for (int rtl = 0; rtl < 2; ++rtl) {
        f32x4 b4 = *(const f32x4*)(qkv_b + h * 32 + rtl * 16 + quad * 4);
        #pragma unroll
        for (int ct = 0; ct < 4; ++ct) {
            bf16x4 pk;
            #pragma unroll
            for (int r = 0; r < 4; ++r) pk[r] = (bf16_t)((qacc[rtl][ct][r] + b4[r]) * scale);
            int row = ct * 16 + l15;
            *(bf16x4*)(buf0 + row * 64 + ((rtl * 32 + quad * 8) ^ ((row & 3) << 4))) = pk;
        }
    }
    bf16x8 qa[4];
    #pragma unroll
    for (int nt = 0; nt < 4; ++nt) {
        int row = nt * 16 + l15;
        qa[nt] = *(const bf16x8*)(buf0 + row * 64 + ((quad * 16) ^ ((row & 3) << 4)));
    }

    // ---- V -> buf0 as [32][64]sw (overwrites Q region; qa already read)
    #pragma unroll
    for (int rtl = 0; rtl < 2; ++rtl)
        #pragma unroll
        for (int ct = 0; ct < 4; ++ct) {
            int d = rtl * 16 + l15;
            *(bf16x4*)(buf0 + d * 128 + ((ct * 32 + quad * 8) ^ ((d & 7) << 4))) = vpk[ct][rtl];
        }

    // ---- K fragments from kst
    bf16x8 kb[4];
    #pragma unroll
    for (int mt = 0; mt < 4; ++mt) {
        int m = mt * 16 + l15;
        kb[mt] = *(const bf16x8*)(kst + m * 64 + ((quad * 16) ^ ((m & 3) << 4)));
    }

    // ---- S^T + softmax fused per column nt (S^T = mfma(kb, qa): m on quad/reg, n on lanes)
    float inv[4];
    bf16x4 ppk[4][4];   // [mt][nt]
    {
        const int qhi = quad >> 1, qlo = quad & 1;
        const int nwv = (l15 & 7) + 7 - 4 * qlo;   // (nw - mw0 + 7)
        const int nh_ = l15 >> 3;
        #pragma unroll
        for (int nt = 0; nt < 4; ++nt) {
            f32x4 scol[4];
            #pragma unroll
            for (int mt = 0; mt < 4; ++mt)
                scol[mt] = mfma16(kb[mt], qa[nt], (f32x4){0.f,0.f,0.f,0.f});
            const int n = nt * 16 + l15;
            if constexpr (USE_WS) {
                const float* bh = bias_pre + (h << 12) + n * 64;
                #pragma unroll
                for (int mt = 0; mt < 4; ++mt) {
                    f32x4 bv = *(const f32x4*)(bh + mt * 16 + quad * 4);
                    f32x4 mv = *(const f32x4*)(smem + OFF_MASK + n * 256 +
                                               ((mt * 64 + quad * 16) ^ ((n & 7) << 4)));
                    scol[mt] += bv + mv;
                }
            } else {
                #pragma unroll
                for (int mt = 0; mt < 4; ++mt) {
                    f32x4 mv = *(const f32x4*)(smem + OFF_MASK + n * 256 +
                                               ((mt * 64 + quad * 16) ^ ((n & 7) << 4)));
                    int base = (nt * 2 + nh_ - 2 * mt - qhi + 7) * 15 + nwv;
                    #pragma unroll
                    for (int r = 0; r < 4; ++r)
                        scol[mt][r] += bias_table[(base - r) * NH + h] + mv[r];
                }
            }
            float mx = scol[0][0];
            #pragma unroll
            for (int mt = 0; mt < 4; ++mt)
                #pragma unroll
                for (int r = 0; r < 4; ++r) mx = fmaxf(mx, scol[mt][r]);
            mx = fmaxf(mx, __shfl_xor(mx, 16, 64));
            mx = fmaxf(mx, __shfl_xor(mx, 32, 64));
            float s = 0.f;
            #pragma unroll
            for (int mt = 0; mt < 4; ++mt)
                #pragma unroll
                for (int r = 0; r < 4; ++r) {
                    float e = __expf(scol[mt][r] - mx);
                    ppk[mt][nt][r] = (bf16_t)e;
                    s += e;
                }
            s += __shfl_xor(s, 16, 64);
            s += __shfl_xor(s, 32, 64);
            inv[nt] = __builtin_amdgcn_rcpf(s);
        }
    }

    // ---- PV: read vb (before P overwrites V region), then P halves through buf0.
    bf16x8 vb[2][2];
    #pragma unroll
    for (int dt = 0; dt < 2; ++dt)
        #pragma unroll
        for (int ch = 0; ch < 2; ++ch) {
            int d = dt * 16 + l15;
            vb[dt][ch] = *(const bf16x8*)(buf0 + d * 128 + ((ch * 64 + quad * 16) ^ ((d & 7) << 4)));
        }

    f32x4 oaccT[2][4];   // [dt][nt]: d on (quad,reg), n on lanes
    #pragma unroll
    for (int dt = 0; dt < 2; ++dt)
        #pragma unroll
        for (int nt = 0; nt < 4; ++nt) oaccT[dt][nt] = (f32x4){0.f,0.f,0.f,0.f};

    #pragma unroll
    for (int ch = 0; ch < 2; ++ch) {
        #pragma unroll
        for (int mt2 = 0; mt2 < 2; ++mt2) {   // mt = 2*ch + mt2
            #pragma unroll
            for (int nt = 0; nt < 4; ++nt) {
                int row = nt * 16 + l15;
                *(bf16x4*)(buf0 + row * 64 + ((mt2 * 32 + quad * 8) ^ ((row & 3) << 4))) =
                    ppk[2 * ch + mt2][nt];
            }
        }
        #pragma unroll
        for (int nt = 0; nt < 4; ++nt) {
            int row = nt * 16 + l15;
            bf16x8 pb = *(const bf16x8*)(buf0 + row * 64 + ((quad * 16) ^ ((row & 3) << 4)));
            #pragma unroll
            for (int dt = 0; dt < 2; ++dt)
                oaccT[dt][nt] = mfma16(vb[dt][ch], pb, oaccT[dt][nt]);
        }
    }
    __syncthreads();   // all waves done with buf0; region0 becomes o_lds

    // ---- Phase 6: O -> o_lds[n][c] swizzled (normalize by inv here)
    #pragma unroll
    for (int dt = 0; dt < 2; ++dt)
        #pragma unroll
        for (int nt = 0; nt < 4; ++nt) {
            bf16x4 pk;
            #pragma unroll
            for (int r = 0; r < 4; ++r) pk[r] = (bf16_t)(oaccT[dt][nt][r] * inv[nt]);
            int row = nt * 16 + l15;
            *(bf16x4*)(smem + row * 512 +
                       ((h * 64 + dt * 32 + quad * 8) ^ ((row & 7) << 4))) = pk;
        }
    __syncthreads();

    // ---- Phase 7: Y^T[e][n] = proj_w(e,:) . O(n,:); wave w -> e in [w*32, w*32+32)
    {
        f32x4 yacc[2][4];
        #pragma unroll
        for (int rt = 0; rt < 2; ++rt)
            #pragma unroll
            for (int ct = 0; ct < 4; ++ct) yacc[rt][ct] = (f32x4){0.f,0.f,0.f,0.f};

        const int e0r = w * 32 + l15;
        bf16x8 a0 = load_wrow<USE_WS>(proj_wb, proj_w, e0r,      quad * 8);
        bf16x8 a1 = load_wrow<USE_WS>(proj_wb, proj_w, e0r + 16, quad * 8);
        #pragma unroll 1
        for (int kk = 0; kk < 8; ++kk) {
            const int cb = kk * 64 + quad * 16;
            const int c1 = ((kk + 1) & 7) * 32 + quad * 8;
            bf16x8 n0 = load_wrow<USE_WS>(proj_wb, proj_w, e0r,      c1);
            bf16x8 n1 = load_wrow<USE_WS>(proj_wb, proj_w, e0r + 16, c1);
            bf16x8 bfr[4];
            #pragma unroll
            for (int ct = 0; ct < 4; ++ct) {
                int row = ct * 16 + l15;
                bfr[ct] = *(const bf16x8*)(smem + row * 512 + (cb ^ ((row & 7) << 4)));
            }
            #pragma unroll
            for (int ct = 0; ct < 4; ++ct) {
                yacc[0][ct] = mfma16(a0, bfr[ct], yacc[0][ct]);
                yacc[1][ct] = mfma16(a1, bfr[ct], yacc[1][ct]);
            }
            a0 = n0; a1 = n1;
        }
        float* ob = out + (size_t)b * (NTOK * CDIM);
        #pragma unroll
        for (int rt = 0; rt < 2; ++rt) {
            int e0 = w * 32 + rt * 16 + quad * 4;
            f32x4 pb4 = *(const f32x4*)(proj_b + e0);
            #pragma unroll
            for (int ct = 0; ct < 4; ++ct) {
                int n = ct * 16 + l15;
                f32x4 r = yacc[rt][ct] + pb4;
                *(f32x4*)(ob + n * 256 + e0) = r;
            }
        }
    }
}

// One-time: fp32 weights -> bf16 workspace, plus bias_pre[h][n][m] f32 table.
__global__ void cvt_weights(const float* __restrict__ qkv_w,
                            const float* __restrict__ proj_w,
                            const float* __restrict__ bias_table,
                            bf16_t* __restrict__ qkv_wb,
                            bf16_t* __restrict__ proj_wb,
                            float* __restrict__ bias_pre)
{
    int i = blockIdx.x * 256 + threadIdx.x;
    if (i < 65536) {
        int base = i * 4;
        const float* src; bf16_t* dst;
        if (base < 196608) { src = qkv_w + base; dst = qkv_wb + base; }
        else { base -= 196608; src = proj_w + base; dst = proj_wb + base; }
        f32x4 v = *(const f32x4*)src;
        bf16x4 o;
        #pragma unroll
        for (int j = 0; j < 4; ++j) o[j] = (bf16_t)v[j];
        *(bf16x4*)dst = o;
    } else {
        int base = (i - 65536) * 4;          // index into [8][64][64]
        int h = base >> 12, n = (base >> 6) & 63, m0 = base & 63;
        f32x4 o;
        #pragma unroll
        for (int j = 0; j < 4; ++j) {
            int m = m0 + j;
            int idx = ((n >> 3) - (m >> 3) + 7) * 15 + ((n & 7) - (m & 7) + 7);
            o[j] = bias_table[idx * NH + h];
        }
        *(f32x4*)(bias_pre + base) = o;
    }
}

extern "C" void kernel_launch(void* const* d_in, const int* in_sizes, int n_in,
                              void* d_out, int out_size, void* d_ws, size_t ws_size,
                              hipStream_t stream) {
    const float* x          = (const float*)d_in[0];
    const float* mask       = (const float*)d_in[1];
    const float* qkv_w      = (const float*)d_in[2];
    const float* qkv_b      = (const float*)d_in[3];
    const float* proj_w     = (const float*)d_in[4];
    const float* proj_b     = (const float*)d_in[5];
    const float* bias_table = (const float*)d_in[6];
    float* out = (float*)d_out;

    const size_t ws_needed = 524288 + 524288;   // bf16 weights + f32 bias_pre
    if (ws_size >= ws_needed) {
        bf16_t* qkv_wb  = (bf16_t*)d_ws;
        bf16_t* proj_wb = qkv_wb + 196608;
        float*  bias_pre = (float*)((unsigned char*)d_ws + 524288);
        cvt_weights<<<384, 256, 0, stream>>>(qkv_w, proj_w, bias_table, qkv_wb, proj_wb, bias_pre);
        win_attn_kernel<true><<<NWIN, 512, 0, stream>>>(
            x, mask, qkv_w, qkv_b, proj_w, proj_b, bias_table, qkv_wb, proj_wb, bias_pre, out);
    } else {
        win_attn_kernel<false><<<NWIN, 512, 0, stream>>>(
            x, mask, qkv_w, qkv_b, proj_w, proj_b, bias_table, nullptr, nullptr, nullptr, out);
    }
}